// Round 3
// baseline (14362.045 us; speedup 1.0000x reference)
//
#include <hip/hip_runtime.h>

#define VOCAB   32000
#define WORDVEC 256
#define HIDDEN  512
#define TSTEPS  256
#define NBATCH  16
#define NROWS   (TSTEPS*NBATCH)   // 4096
#define GATES   (4*HIDDEN)        // 2048
#define NVB     125               // 32000/256
#define NWG     32                // LSTM worker WGs (32 x 16 hidden units)
#define NLAUNCH 256               // launched WGs for XCD election
#define SPINMAX 128               // bounded sc0 poll before agent fallback

typedef __attribute__((ext_vector_type(8))) short short8;
typedef __attribute__((ext_vector_type(4))) float f32x4;
typedef unsigned long long u64;

#define AGLOAD(p) __hip_atomic_load((p), __ATOMIC_RELAXED, __HIP_MEMORY_SCOPE_AGENT)

__device__ __forceinline__ unsigned short f2bf(float x){
    union { float f; unsigned int u; } v; v.f = x;
    unsigned int r = v.u + 0x7fffu + ((v.u >> 16) & 1u);
    return (unsigned short)(r >> 16);
}

__device__ __forceinline__ int xcc_id(){
    int x;
    asm volatile("s_getreg_b32 %0, hwreg(HW_REG_XCC_ID)" : "=s"(x));
    return x & 7;
}

// ---------------------------------------------------------------- K0a:
// W_vocab (fp32 [512][32000]) -> WvP: MFMA-B-fragment-linear bf16.
__global__ __launch_bounds__(256) void wv_pack(const float* __restrict__ Wv, unsigned short* __restrict__ WvP){
    __shared__ float s[64][65];
    int v0 = blockIdx.x * 64;     // 500 blocks
    int k0 = blockIdx.y * 64;     // 8 blocks
    int tid = threadIdx.x;
    for (int i = 0; i < 16; ++i){
        int lin = tid + i*256;
        int kk = lin >> 6, vv = lin & 63;
        s[kk][vv] = Wv[(long)(k0+kk)*VOCAB + v0 + vv];
    }
    __syncthreads();
    for (int i = 0; i < 2; ++i){
        int lr = tid + i*256;          // 0..511 lane-rows
        int f  = lr >> 6;              // 0..7: vbl(0..3) x ktl(0..1)
        int vbl = f >> 1, ktl = f & 1;
        int L = lr & 63, q = L >> 4, ln = L & 15;
        short8 o;
        #pragma unroll
        for (int j = 0; j < 8; ++j)
            o[j] = (short)f2bf(s[ktl*32 + q*8 + j][vbl*16 + ln]);
        long vb = blockIdx.x*4 + vbl;
        long kt = blockIdx.y*2 + ktl;
        *(short8*)(WvP + ((vb*16 + kt)*64 + L)*8) = o;
    }
}

// ---------------------------------------------------------------- K0b:
// Wh (fp32 [512][2048]) -> Whp: per-WG MFMA-B-fragment-ordered bf16 image.
__global__ void whp_prep(const float* __restrict__ Wh, unsigned short* __restrict__ Whp){
    int w = blockIdx.x; int tid = threadIdx.x;   // 32 blocks x 256 thr
    for (int item = tid; item < 4096; item += 256){
        int f = item >> 6;          // 0..63
        int L = item & 63;
        int kt = f >> 2, nt = f & 3;
        int q = L >> 4, ln = L & 15;
        int col = nt*HIDDEN + w*16 + ln;   // gate nt, unit w*16+ln
        short8 vvec;
        for (int jj = 0; jj < 8; ++jj){
            int k = kt*32 + q*8 + jj;
            vvec[jj] = (short)f2bf(Wh[(long)k*GATES + col]);
        }
        *(short8*)(Whp + ((long)w*4096 + item)*8) = vvec;
    }
}

// ---------------------------------------------------------------- K0c:
// h_0 into BOTH exchange buffers (primary + backup) as tagged pairs; zero ctl.
__global__ void hg_init(const float* __restrict__ h_init, u64* __restrict__ hx,
                        u64* __restrict__ hxB, int* __restrict__ ctl){
    if (blockIdx.x == 0 && threadIdx.x < 16) ctl[threadIdx.x] = 0;
    int p = blockIdx.x*256 + threadIdx.x;   // 4096 pairs
    int fq = p >> 6;
    int j  = (p & 3) * 2;
    int u0 = (fq>>2)*32 + (fq&3)*8 + j;
    u64 pk = (u64)f2bf(h_init[u0]) | ((u64)f2bf(h_init[u0+1]) << 16);   // tag 0
    hx[p]  = pk;
    hxB[p] = pk;
}

// ---------------------------------------------------------------- K1:
// xw[r=t*16+n][k] = b[k] + sum_d W_embed[cap_in[n][t]][d] * Wx[d][k]   (fp32)
__global__ __launch_bounds__(256) void embed_xw(const int* __restrict__ captions,
        const float* __restrict__ Wemb, const float* __restrict__ Wx,
        const float* __restrict__ b, float* __restrict__ xw){
    __shared__ float xs[8][WORDVEC];
    __shared__ int toks[8];
    int tid = threadIdx.x;
    int r0 = blockIdx.x * 8;
    if (tid < 8){
        int r = r0 + tid; int t = r >> 4, n = r & 15;
        toks[tid] = captions[n*257 + t];
    }
    __syncthreads();
    for (int i = 0; i < 8; ++i){
        int lin = tid + i*256;
        int ri = lin >> 8, d = lin & 255;
        xs[ri][d] = Wemb[(long)toks[ri]*WORDVEC + d];
    }
    __syncthreads();
    float4 b0 = *(const float4*)(b + tid*4);
    float4 b1 = *(const float4*)(b + 1024 + tid*4);
    float acc[8][8];
    for (int ri = 0; ri < 8; ++ri){
        acc[ri][0]=b0.x; acc[ri][1]=b0.y; acc[ri][2]=b0.z; acc[ri][3]=b0.w;
        acc[ri][4]=b1.x; acc[ri][5]=b1.y; acc[ri][6]=b1.z; acc[ri][7]=b1.w;
    }
    for (int d = 0; d < WORDVEC; ++d){
        float4 w0 = *(const float4*)(Wx + (long)d*GATES + tid*4);
        float4 w1 = *(const float4*)(Wx + (long)d*GATES + 1024 + tid*4);
        #pragma unroll
        for (int ri = 0; ri < 8; ++ri){
            float xv = xs[ri][d];
            acc[ri][0] += xv*w0.x; acc[ri][1] += xv*w0.y;
            acc[ri][2] += xv*w0.z; acc[ri][3] += xv*w0.w;
            acc[ri][4] += xv*w1.x; acc[ri][5] += xv*w1.y;
            acc[ri][6] += xv*w1.z; acc[ri][7] += xv*w1.w;
        }
    }
    for (int ri = 0; ri < 8; ++ri){
        float4 o0 = {acc[ri][0],acc[ri][1],acc[ri][2],acc[ri][3]};
        float4 o1 = {acc[ri][4],acc[ri][5],acc[ri][6],acc[ri][7]};
        *(float4*)(xw + (long)(r0+ri)*GATES + tid*4) = o0;
        *(float4*)(xw + (long)(r0+ri)*GATES + 1024 + tid*4) = o1;
    }
}

// ---------------------------------------------------------------- K2:
// Batched LSTM. Round 10: single-XCD election + sc0 (local-L2) exchange,
// now HANG-PROOF: bounded sc0 poll (SPINMAX) -> fallback to the verified
// round-0 agent-scope protocol on a backup buffer. Both buffers written
// every step; coherence domains never mixed.
__global__ __launch_bounds__(256) void lstm_mfma(const float* __restrict__ xw,
        const unsigned short* __restrict__ Whp, u64* __restrict__ hx,
        u64* __restrict__ hxB, unsigned short* __restrict__ hsP, int* __restrict__ ctl){
    __shared__ unsigned int hstage[4096];   // 16 KB: h_t as bf16 pairs (tags stripped)
    __shared__ float a_s[4][16][16];        // 4 KB
    __shared__ int roleS;
    int tid = threadIdx.x;       // 0..255

    // ---- XCD election: first XCD to fill 32 tickets wins; its 32 WGs work.
    if (tid == 0){
        int myx = xcc_id();
        int tk = atomicAdd(&ctl[myx], 1);            // device-scope, one-time
        int role = -1;
        if (tk < NWG){
            if (tk == NWG-1) atomicCAS(&ctl[8], 0, myx + 1);
            int win;
            do { win = AGLOAD(&ctl[8]); } while (win == 0);
            if (win == myx + 1) role = tk;
        }
        roleS = role;
    }
    __syncthreads();
    int w = roleS;               // 0..31 for workers, -1 otherwise
    if (w < 0) return;

    int wv = tid >> 6;           // wave = gate = N-tile (0..3)
    int L = tid & 63;
    int q = L >> 4, ln = L & 15;
    int s_idx = tid >> 4, jl = tid & 15;   // (sequence, local hidden unit)

    // Wh B-fragments -> registers (wave wv uses fragments kt*4+wv only)
    short8 bw[16];
    #pragma unroll
    for (int kt = 0; kt < 16; ++kt)
        bw[kt] = *(const short8*)(Whp + ((long)w*4096 + (kt*4+wv)*64 + L)*8);

    float c_r = 0.f;
    int fq_pub = (w>>1)*4 + (w&1)*2 + (jl>>3);
    int pubIdx = fq_pub*64 + s_idx*4 + ((jl>>1)&3);
    int kt_h = w >> 1;
    int q_h  = ((w & 1) << 1) | (jl >> 3);
    int j_h  = jl & 7;

    for (int t = 0; t < TSTEPS; ++t){
        // xw loads first: HBM latency overlaps the poll
        long xb = (long)(t*16 + s_idx)*GATES + w*16 + jl;
        float xg0 = xw[xb], xg1 = xw[xb+512], xg2 = xw[xb+1024], xg3 = xw[xb+1536];

        const u64* hr  = hx  + (t & 1)*4096;
        const u64* hrB = hxB + (t & 1)*4096;
        u64*       hw  = hx  + ((t+1) & 1)*4096;
        u64*       hwB = hxB + ((t+1) & 1)*4096;

        // ---- fast poll: bounded rounds of 16 sc0 (local-L2) u64 loads
        const u64* hrt = hr + tid;
        u64 v0,v1,v2,v3,v4,v5,v6,v7,v8,v9,v10,v11,v12,v13,v14,v15;
        u64 tt = (u64)(unsigned)t;
        u64 bad;
        int spins = 0;
        for (;;){
            asm volatile(
                "global_load_dwordx2 %[o0],  %[a0], off sc0\n\t"
                "global_load_dwordx2 %[o1],  %[a0], off offset:2048 sc0\n\t"
                "global_load_dwordx2 %[o2],  %[a1], off sc0\n\t"
                "global_load_dwordx2 %[o3],  %[a1], off offset:2048 sc0\n\t"
                "global_load_dwordx2 %[o4],  %[a2], off sc0\n\t"
                "global_load_dwordx2 %[o5],  %[a2], off offset:2048 sc0\n\t"
                "global_load_dwordx2 %[o6],  %[a3], off sc0\n\t"
                "global_load_dwordx2 %[o7],  %[a3], off offset:2048 sc0\n\t"
                "global_load_dwordx2 %[o8],  %[a4], off sc0\n\t"
                "global_load_dwordx2 %[o9],  %[a4], off offset:2048 sc0\n\t"
                "global_load_dwordx2 %[o10], %[a5], off sc0\n\t"
                "global_load_dwordx2 %[o11], %[a5], off offset:2048 sc0\n\t"
                "global_load_dwordx2 %[o12], %[a6], off sc0\n\t"
                "global_load_dwordx2 %[o13], %[a6], off offset:2048 sc0\n\t"
                "global_load_dwordx2 %[o14], %[a7], off sc0\n\t"
                "global_load_dwordx2 %[o15], %[a7], off offset:2048 sc0\n\t"
                "s_waitcnt vmcnt(0)"
                : [o0]"=&v"(v0),[o1]"=&v"(v1),[o2]"=&v"(v2),[o3]"=&v"(v3),
                  [o4]"=&v"(v4),[o5]"=&v"(v5),[o6]"=&v"(v6),[o7]"=&v"(v7),
                  [o8]"=&v"(v8),[o9]"=&v"(v9),[o10]"=&v"(v10),[o11]"=&v"(v11),
                  [o12]"=&v"(v12),[o13]"=&v"(v13),[o14]"=&v"(v14),[o15]"=&v"(v15)
                : [a0]"v"(hrt),[a1]"v"(hrt+512),[a2]"v"(hrt+1024),[a3]"v"(hrt+1536),
                  [a4]"v"(hrt+2048),[a5]"v"(hrt+2560),[a6]"v"(hrt+3072),[a7]"v"(hrt+3584)
                : "memory");
            bad = ((v0>>32)^tt)|((v1>>32)^tt)|((v2>>32)^tt)|((v3>>32)^tt)
                | ((v4>>32)^tt)|((v5>>32)^tt)|((v6>>32)^tt)|((v7>>32)^tt)
                | ((v8>>32)^tt)|((v9>>32)^tt)|((v10>>32)^tt)|((v11>>32)^tt)
                | ((v12>>32)^tt)|((v13>>32)^tt)|((v14>>32)^tt)|((v15>>32)^tt);
            if (!bad) break;
            if (++spins >= SPINMAX) break;
        }
        if (bad){
            // ---- fallback: verified round-0 protocol (agent loads, backup buf)
            const u64* hrBt = hrB + tid;
            for (;;){
                v0  = AGLOAD(hrBt);        v1  = AGLOAD(hrBt+256);
                v2  = AGLOAD(hrBt+512);    v3  = AGLOAD(hrBt+768);
                v4  = AGLOAD(hrBt+1024);   v5  = AGLOAD(hrBt+1280);
                v6  = AGLOAD(hrBt+1536);   v7  = AGLOAD(hrBt+1792);
                v8  = AGLOAD(hrBt+2048);   v9  = AGLOAD(hrBt+2304);
                v10 = AGLOAD(hrBt+2560);   v11 = AGLOAD(hrBt+2816);
                v12 = AGLOAD(hrBt+3072);   v13 = AGLOAD(hrBt+3328);
                v14 = AGLOAD(hrBt+3584);   v15 = AGLOAD(hrBt+3840);
                u64 bb = ((v0>>32)^tt)|((v1>>32)^tt)|((v2>>32)^tt)|((v3>>32)^tt)
                       | ((v4>>32)^tt)|((v5>>32)^tt)|((v6>>32)^tt)|((v7>>32)^tt)
                       | ((v8>>32)^tt)|((v9>>32)^tt)|((v10>>32)^tt)|((v11>>32)^tt)
                       | ((v12>>32)^tt)|((v13>>32)^tt)|((v14>>32)^tt)|((v15>>32)^tt);
                if (!bb) break;
            }
        }
        hstage[tid+0*256]=(unsigned)v0;   hstage[tid+1*256]=(unsigned)v1;
        hstage[tid+2*256]=(unsigned)v2;   hstage[tid+3*256]=(unsigned)v3;
        hstage[tid+4*256]=(unsigned)v4;   hstage[tid+5*256]=(unsigned)v5;
        hstage[tid+6*256]=(unsigned)v6;   hstage[tid+7*256]=(unsigned)v7;
        hstage[tid+8*256]=(unsigned)v8;   hstage[tid+9*256]=(unsigned)v9;
        hstage[tid+10*256]=(unsigned)v10; hstage[tid+11*256]=(unsigned)v11;
        hstage[tid+12*256]=(unsigned)v12; hstage[tid+13*256]=(unsigned)v13;
        hstage[tid+14*256]=(unsigned)v14; hstage[tid+15*256]=(unsigned)v15;
        __syncthreads();   // S1: stage complete (also orders vs prev a_s reads)

        // ---- MFMA: A-frag (kt,q,ln) = 4 contiguous u32 (linear sweep)
        f32x4 acc = {0.f,0.f,0.f,0.f};
        #pragma unroll
        for (int kt = 0; kt < 16; ++kt){
            short8 a = *(const short8*)((const unsigned short*)hstage + (kt*256 + q*64 + ln*4)*2);
            acc = __builtin_amdgcn_mfma_f32_16x16x32_bf16(a, bw[kt], acc, 0, 0, 0);
        }
        #pragma unroll
        for (int r = 0; r < 4; ++r) a_s[wv][q*4 + r][ln] = acc[r];
        __syncthreads();   // S2: a_s complete (also: all hstage reads done)

        // ---- gate phase
        float ai = a_s[0][s_idx][jl] + xg0;
        float af = a_s[1][s_idx][jl] + xg1;
        float ao = a_s[2][s_idx][jl] + xg2;
        float ag = a_s[3][s_idx][jl] + xg3;
        float ig = 1.f/(1.f + __expf(-ai));
        float fg = 1.f/(1.f + __expf(-af));
        float og = 1.f/(1.f + __expf(-ao));
        float gg = 2.f/(1.f + __expf(-2.f*ag)) - 1.f;
        c_r = fg*c_r + ig*gg;
        float hv = og * (2.f/(1.f + __expf(-2.f*c_r)) - 1.f);
        unsigned short hb = f2bf(hv);

        // ---- publish: pack {tag=t+1 | h[jl+1] | h[jl]}; sc0 (fast) + agent (backup)
        int hv32 = (int)hb;
        int other = __shfl(hv32, L ^ 1);
        if ((jl & 1) == 0){
            u64 pk = (u64)(unsigned short)hv32
                   | ((u64)(unsigned short)other << 16)
                   | ((u64)(unsigned)(t+1) << 32);
            asm volatile("global_store_dwordx2 %0, %1, off sc0"
                         :: "v"(hw + pubIdx), "v"(pk) : "memory");
            __hip_atomic_store(hwB + pubIdx, pk, __ATOMIC_RELAXED, __HIP_MEMORY_SCOPE_AGENT);
        }
        // hsP history store, A-fragment-linear (off critical path, plain cached)
        int rb = s_idx*16 + (t >> 4);
        hsP[(((long)(rb*16 + kt_h))*64 + q_h*16 + (t & 15))*8 + j_h] = hb;
    }
}

// ---------------------------------------------------------------- K3:
// Fused vocab GEMM + per-row softmax partials. BM=64, BN=256, 256 thr (4 waves).
__global__ __launch_bounds__(256) void vocab_gemm(const unsigned short* __restrict__ hsP,
        const unsigned short* __restrict__ WvP, const float* __restrict__ bvoc,
        const int* __restrict__ captions, float* __restrict__ pmax,
        float* __restrict__ psum, float* __restrict__ tlog){
    int bm = blockIdx.x;    // 0..63
    int bn = blockIdx.y;    // 0..124
    int tid = threadIdx.x;
    int wv = tid >> 6, L = tid & 63;
    int q = L >> 4, ln = L & 15;
    __shared__ int   tgt_s[64];
    __shared__ float wmax_s[4][64], wsum_s[4][64];
    if (tid < 64){
        int rg = bm*64 + tid;
        tgt_s[tid] = captions[(rg >> 8)*257 + (rg & 255) + 1];
    }
    __syncthreads();
    f32x4 acc[4][4];
    for (int mt=0;mt<4;++mt) for (int nt=0;nt<4;++nt) acc[mt][nt] = (f32x4){0.f,0.f,0.f,0.f};
    int colb = bn*256 + wv*64;
    const unsigned short* aB = hsP + ((long)(bm*4)*16)*512;        // rb = bm*4 + mt
    const unsigned short* bB = WvP + ((long)(bn*16 + wv*4)*16)*512; // vb = bn*16+wv*4+nt
    #pragma unroll 4
    for (int kt = 0; kt < 16; ++kt){
        short8 a[4], bb[4];
        #pragma unroll
        for (int mt=0;mt<4;++mt)
            a[mt] = *(const short8*)(aB + ((long)(mt*16 + kt)*64 + L)*8);
        #pragma unroll
        for (int nt=0;nt<4;++nt)
            bb[nt] = *(const short8*)(bB + ((long)(nt*16 + kt)*64 + L)*8);
        #pragma unroll
        for (int mt=0;mt<4;++mt)
            #pragma unroll
            for (int nt=0;nt<4;++nt)
                acc[mt][nt] = __builtin_amdgcn_mfma_f32_16x16x32_bf16(a[mt], bb[nt], acc[mt][nt], 0,0,0);
    }
    float bv[4];
    #pragma unroll
    for (int nt=0;nt<4;++nt) bv[nt] = bvoc[colb + nt*16 + ln];
    #pragma unroll
    for (int mt=0;mt<4;++mt) for (int nt=0;nt<4;++nt) for (int r=0;r<4;++r)
        acc[mt][nt][r] += bv[nt];
    #pragma unroll
    for (int mt=0;mt<4;++mt) for (int r=0;r<4;++r){
        int rl = mt*16 + q*4 + r;
        int tg = tgt_s[rl] - colb;
        if (tg >= 0 && tg < 64){
            int nt = tg >> 4;
            if ((tg & 15) == ln) tlog[bm*64 + rl] = acc[mt][nt][r];
        }
    }
    #pragma unroll
    for (int mt=0;mt<4;++mt){
        #pragma unroll
        for (int r=0;r<4;++r){
            float m = fmaxf(fmaxf(acc[mt][0][r],acc[mt][1][r]), fmaxf(acc[mt][2][r],acc[mt][3][r]));
            for (int d=1; d<16; d<<=1) m = fmaxf(m, __shfl_xor(m, d, 16));
            float s = __expf(acc[mt][0][r]-m) + __expf(acc[mt][1][r]-m)
                    + __expf(acc[mt][2][r]-m) + __expf(acc[mt][3][r]-m);
            for (int d=1; d<16; d<<=1) s += __shfl_xor(s, d, 16);
            if (ln == 0){ int rl = mt*16 + q*4 + r; wmax_s[wv][rl] = m; wsum_s[wv][rl] = s; }
        }
    }
    __syncthreads();
    if (tid < 64){
        float M = fmaxf(fmaxf(wmax_s[0][tid],wmax_s[1][tid]), fmaxf(wmax_s[2][tid],wmax_s[3][tid]));
        float S = 0.f;
        for (int ww=0; ww<4; ++ww) S += wsum_s[ww][tid]*__expf(wmax_s[ww][tid]-M);
        pmax[(long)bn*NROWS + bm*64 + tid] = M;
        psum[(long)bn*NROWS + bm*64 + tid] = S;
    }
}

// ---------------------------------------------------------------- K4:
// combine 125 partials per row -> lse -> masked NLL -> loss/N
__global__ __launch_bounds__(256) void reduce_loss(const float* __restrict__ pmax,
        const float* __restrict__ psum, const float* __restrict__ tlog,
        const int* __restrict__ captions, float* __restrict__ out){
    int r = blockIdx.x*256 + threadIdx.x;
    float M = -1e30f;
    for (int p=0;p<NVB;++p) M = fmaxf(M, pmax[(long)p*NROWS + r]);
    float S = 0.f;
    for (int p=0;p<NVB;++p) S += psum[(long)p*NROWS + r]*__expf(pmax[(long)p*NROWS + r]-M);
    float lse = M + logf(S);
    float nll = lse - tlog[r];
    int tok = captions[(r >> 8)*257 + (r & 255) + 1];
    float val = (tok != 0) ? nll : 0.f;
    __shared__ float red[256];
    red[threadIdx.x] = val; __syncthreads();
    for (int s=128; s>0; s>>=1){
        if (threadIdx.x < s) red[threadIdx.x] += red[threadIdx.x+s];
        __syncthreads();
    }
    if (threadIdx.x == 0) atomicAdd(out, red[0] * (1.0f/16.0f));
}

// ---------------------------------------------------------------- launch
extern "C" void kernel_launch(void* const* d_in, const int* in_sizes, int n_in,
                              void* d_out, int out_size, void* d_ws, size_t ws_size,
                              hipStream_t stream){
    const int*   captions = (const int*)  d_in[0];
    const float* Wemb     = (const float*)d_in[1];
    const float* Wx       = (const float*)d_in[2];
    const float* Wh       = (const float*)d_in[3];
    const float* b        = (const float*)d_in[4];
    const float* Wv       = (const float*)d_in[5];
    const float* bvoc     = (const float*)d_in[6];
    const float* h_init   = (const float*)d_in[7];

    char* ws = (char*)d_ws;
    float*          xw   = (float*)         (ws + 0);          // 33554432 B
    unsigned short* WvP  = (unsigned short*)(ws + 33554432);   // 32768000 B
    unsigned short* hsP  = (unsigned short*)(ws + 66322432);   //  4194304 B
    float*          pmax = (float*)         (ws + 70516736);   //  2048000 B
    float*          psum = (float*)         (ws + 72564736);   //  2048000 B
    float*          tlog = (float*)         (ws + 74612736);   //    16384 B
    unsigned short* Whp  = (unsigned short*)(ws + 74629120);   //  2097152 B
    u64*            hx   = (u64*)           (ws + 76726272);   //    65536 B (2 bufs x 4096 u64)
    int*            ctl  = (int*)           (ws + 76791808);   //       64 B (8 cnt + winner)
    // backup exchange overlaid on pmax region (pmax only written AFTER lstm, stream-ordered)
    u64*            hxB  = (u64*)           (ws + 70516736);   //    65536 B (2 bufs x 4096 u64)

    float* out_f = (float*)d_out;

    (void)hipMemsetAsync(d_out, 0, sizeof(float), stream);

    hipLaunchKernelGGL(wv_pack,      dim3(500, 8), dim3(256), 0, stream, Wv, WvP);
    hipLaunchKernelGGL(whp_prep,     dim3(NWG),    dim3(256), 0, stream, Wh, Whp);
    hipLaunchKernelGGL(hg_init,      dim3(16),     dim3(256), 0, stream, h_init, hx, hxB, ctl);
    hipLaunchKernelGGL(embed_xw,     dim3(512),    dim3(256), 0, stream, captions, Wemb, Wx, b, xw);
    hipLaunchKernelGGL(lstm_mfma,    dim3(NLAUNCH),dim3(256), 0, stream, xw, Whp, hx, hxB, hsP, ctl);
    hipLaunchKernelGGL(vocab_gemm,   dim3(64,NVB), dim3(256), 0, stream, hsP, WvP, bvoc, captions, pmax, psum, tlog);
    hipLaunchKernelGGL(reduce_loss,  dim3(16),     dim3(256), 0, stream, pmax, psum, tlog, captions, out_f);
}

// Round 4
// 1534.108 us; speedup vs baseline: 9.3618x; 9.3618x over previous
//
#include <hip/hip_runtime.h>

#define VOCAB   32000
#define WORDVEC 256
#define HIDDEN  512
#define TSTEPS  256
#define NBATCH  16
#define NROWS   (TSTEPS*NBATCH)   // 4096
#define GATES   (4*HIDDEN)        // 2048
#define NVB     125               // 32000/256
#define NWG     32                // LSTM worker WGs (32 x 16 hidden units)
#define NWVT    4000              // wv_pack tiles (500 x 8)

typedef __attribute__((ext_vector_type(8))) short short8;
typedef __attribute__((ext_vector_type(4))) float f32x4;
typedef unsigned long long u64;

#define AGLOAD(p) __hip_atomic_load((p), __ATOMIC_RELAXED, __HIP_MEMORY_SCOPE_AGENT)

__device__ __forceinline__ unsigned short f2bf(float x){
    union { float f; unsigned int u; } v; v.f = x;
    unsigned int r = v.u + 0x7fffu + ((v.u >> 16) & 1u);
    return (unsigned short)(r >> 16);
}

// ---------------------------------------------------------------- K_prep:
// One launch, three independent jobs selected by blockIdx.x:
//   [0,512)    embed_xw  : xw[r][k] = b[k] + W_embed[tok]@Wx
//   [512,544)  whp_prep  : Wh -> per-WG MFMA-B-fragment bf16 image
//   [544,560)  hg_init   : h_0 -> tagged-pair exchange buffer 0
__global__ __launch_bounds__(256) void prep_all(const int* __restrict__ captions,
        const float* __restrict__ Wemb, const float* __restrict__ Wx,
        const float* __restrict__ b, float* __restrict__ xw,
        const float* __restrict__ Wh, unsigned short* __restrict__ Whp,
        const float* __restrict__ h_init, u64* __restrict__ hx){
    __shared__ float xs[8][WORDVEC];
    __shared__ int toks[8];
    int bid = blockIdx.x;
    int tid = threadIdx.x;
    if (bid < 512){
        // ---------------- embed_xw ----------------
        int r0 = bid * 8;
        if (tid < 8){
            int r = r0 + tid; int t = r >> 4, n = r & 15;
            toks[tid] = captions[n*257 + t];
        }
        __syncthreads();
        for (int i = 0; i < 8; ++i){
            int lin = tid + i*256;
            int ri = lin >> 8, d = lin & 255;
            xs[ri][d] = Wemb[(long)toks[ri]*WORDVEC + d];
        }
        __syncthreads();
        float4 b0 = *(const float4*)(b + tid*4);
        float4 b1 = *(const float4*)(b + 1024 + tid*4);
        float acc[8][8];
        for (int ri = 0; ri < 8; ++ri){
            acc[ri][0]=b0.x; acc[ri][1]=b0.y; acc[ri][2]=b0.z; acc[ri][3]=b0.w;
            acc[ri][4]=b1.x; acc[ri][5]=b1.y; acc[ri][6]=b1.z; acc[ri][7]=b1.w;
        }
        for (int d = 0; d < WORDVEC; ++d){
            float4 w0 = *(const float4*)(Wx + (long)d*GATES + tid*4);
            float4 w1 = *(const float4*)(Wx + (long)d*GATES + 1024 + tid*4);
            #pragma unroll
            for (int ri = 0; ri < 8; ++ri){
                float xv = xs[ri][d];
                acc[ri][0] += xv*w0.x; acc[ri][1] += xv*w0.y;
                acc[ri][2] += xv*w0.z; acc[ri][3] += xv*w0.w;
                acc[ri][4] += xv*w1.x; acc[ri][5] += xv*w1.y;
                acc[ri][6] += xv*w1.z; acc[ri][7] += xv*w1.w;
            }
        }
        for (int ri = 0; ri < 8; ++ri){
            float4 o0 = {acc[ri][0],acc[ri][1],acc[ri][2],acc[ri][3]};
            float4 o1 = {acc[ri][4],acc[ri][5],acc[ri][6],acc[ri][7]};
            *(float4*)(xw + (long)(r0+ri)*GATES + tid*4) = o0;
            *(float4*)(xw + (long)(r0+ri)*GATES + 1024 + tid*4) = o1;
        }
    } else if (bid < 544){
        // ---------------- whp_prep ----------------
        int w = bid - 512;
        for (int item = tid; item < 4096; item += 256){
            int f = item >> 6;          // 0..63
            int L = item & 63;
            int kt = f >> 2, nt = f & 3;
            int q = L >> 4, ln = L & 15;
            int col = nt*HIDDEN + w*16 + ln;   // gate nt, unit w*16+ln
            short8 vvec;
            for (int jj = 0; jj < 8; ++jj){
                int k = kt*32 + q*8 + jj;
                vvec[jj] = (short)f2bf(Wh[(long)k*GATES + col]);
            }
            *(short8*)(Whp + ((long)w*4096 + item)*8) = vvec;
        }
    } else {
        // ---------------- hg_init ----------------
        int p = (bid - 544)*256 + tid;   // 4096 pairs
        int fq = p >> 6;
        int j  = (p & 3) * 2;
        int u0 = (fq>>2)*32 + (fq&3)*8 + j;
        u64 pk = (u64)f2bf(h_init[u0]) | ((u64)f2bf(h_init[u0+1]) << 16);   // tag 0
        hx[p] = pk;
    }
}

// ---------------------------------------------------------------- K2:
// Batched LSTM (verified round-1 protocol: tagged-u64 agent-scope exchange)
// + co-grid wv_pack: blocks >= NWG convert W_vocab tiles while the 32 LSTM
// workers run their latency-bound recurrence on 32 CUs. The two roles share
// nothing -> no deadlock possible; wv blocks simply retire.
__global__ __launch_bounds__(256) void lstm_wv(const float* __restrict__ xw,
        const unsigned short* __restrict__ Whp, u64* __restrict__ hx,
        unsigned short* __restrict__ hsP,
        const float* __restrict__ Wv, unsigned short* __restrict__ WvP){
    __shared__ unsigned int hstage[4096];   // 16 KB (lstm role)
    __shared__ float a_s[4][16][16];        // 4 KB  (lstm role)
    __shared__ float s[64][65];             // 16.6 KB (wv role)
    int tid = threadIdx.x;       // 0..255

    if (blockIdx.x >= NWG){
        // ---------------- wv_pack role ----------------
        int tile = blockIdx.x - NWG;        // 0..3999
        int v0 = (tile >> 3) * 64;          // 500 column-tiles
        int k0 = (tile & 7) * 64;           // 8 row-tiles
        for (int i = 0; i < 16; ++i){
            int lin = tid + i*256;
            int kk = lin >> 6, vv = lin & 63;
            s[kk][vv] = Wv[(long)(k0+kk)*VOCAB + v0 + vv];
        }
        __syncthreads();
        for (int i = 0; i < 2; ++i){
            int lr = tid + i*256;          // 0..511 lane-rows
            int f  = lr >> 6;              // 0..7: vbl(0..3) x ktl(0..1)
            int vbl = f >> 1, ktl = f & 1;
            int L = lr & 63, q = L >> 4, ln = L & 15;
            short8 o;
            #pragma unroll
            for (int j = 0; j < 8; ++j)
                o[j] = (short)f2bf(s[ktl*32 + q*8 + j][vbl*16 + ln]);
            long vb = (long)(tile >> 3)*4 + vbl;
            long kt = (long)(tile & 7)*2 + ktl;
            *(short8*)(WvP + ((vb*16 + kt)*64 + L)*8) = o;
        }
        return;
    }

    // ---------------- lstm role (verified round-1 code) ----------------
    int w = blockIdx.x;          // 0..31
    int wv = tid >> 6;           // wave = gate = N-tile (0..3)
    int L = tid & 63;
    int q = L >> 4, ln = L & 15;
    int s_idx = tid >> 4, jl = tid & 15;   // (sequence, local hidden unit)

    // Wh B-fragments -> registers (wave wv uses fragments kt*4+wv only)
    short8 bw[16];
    #pragma unroll
    for (int kt = 0; kt < 16; ++kt)
        bw[kt] = *(const short8*)(Whp + ((long)w*4096 + (kt*4+wv)*64 + L)*8);

    float c_r = 0.f;
    int fq_pub = (w>>1)*4 + (w&1)*2 + (jl>>3);
    int pubIdx = fq_pub*64 + s_idx*4 + ((jl>>1)&3);
    int kt_h = w >> 1;
    int q_h  = ((w & 1) << 1) | (jl >> 3);
    int j_h  = jl & 7;

    for (int t = 0; t < TSTEPS; ++t){
        // xw loads first: HBM latency overlaps the poll
        long xb = (long)(t*16 + s_idx)*GATES + w*16 + jl;
        float xg0 = xw[xb], xg1 = xw[xb+512], xg2 = xw[xb+1024], xg3 = xw[xb+1536];

        const u64* hr = hx + (t & 1)*4096;
        u64*       hw = hx + ((t+1) & 1)*4096;

        // ---- poll + stage: 16 coalesced u64/thread, spin until all tags == t
        u64 v[16];
        #pragma unroll
        for (int i = 0; i < 16; ++i)
            v[i] = AGLOAD(hr + tid + i*256);
        for (;;){
            u64 bad = 0;
            #pragma unroll
            for (int i = 0; i < 16; ++i) bad |= (v[i] >> 32) ^ (u64)(unsigned)t;
            if (!bad) break;
            #pragma unroll
            for (int i = 0; i < 16; ++i)
                v[i] = AGLOAD(hr + tid + i*256);
        }
        #pragma unroll
        for (int i = 0; i < 16; ++i) hstage[tid + i*256] = (unsigned)v[i];
        __syncthreads();   // S1: stage complete (also orders vs prev a_s reads)

        // ---- MFMA: A-frag (kt,q,ln) = 4 contiguous u32 (linear sweep)
        f32x4 acc = {0.f,0.f,0.f,0.f};
        #pragma unroll
        for (int kt = 0; kt < 16; ++kt){
            short8 a = *(const short8*)((const unsigned short*)hstage + (kt*256 + q*64 + ln*4)*2);
            acc = __builtin_amdgcn_mfma_f32_16x16x32_bf16(a, bw[kt], acc, 0, 0, 0);
        }
        #pragma unroll
        for (int r = 0; r < 4; ++r) a_s[wv][q*4 + r][ln] = acc[r];
        __syncthreads();   // S2: a_s complete (also: all hstage reads done)

        // ---- gate phase
        float ai = a_s[0][s_idx][jl] + xg0;
        float af = a_s[1][s_idx][jl] + xg1;
        float ao = a_s[2][s_idx][jl] + xg2;
        float ag = a_s[3][s_idx][jl] + xg3;
        float ig = 1.f/(1.f + __expf(-ai));
        float fg = 1.f/(1.f + __expf(-af));
        float og = 1.f/(1.f + __expf(-ao));
        float gg = 2.f/(1.f + __expf(-2.f*ag)) - 1.f;
        c_r = fg*c_r + ig*gg;
        float hv = og * (2.f/(1.f + __expf(-2.f*c_r)) - 1.f);
        unsigned short hb = f2bf(hv);

        // ---- publish: pack {tag=t+1 | h[jl+1] | h[jl]}, fire-and-forget
        int hv32 = (int)hb;
        int other = __shfl(hv32, L ^ 1);
        if ((jl & 1) == 0){
            u64 pk = (u64)(unsigned short)hv32
                   | ((u64)(unsigned short)other << 16)
                   | ((u64)(unsigned)(t+1) << 32);
            __hip_atomic_store(hw + pubIdx, pk, __ATOMIC_RELAXED, __HIP_MEMORY_SCOPE_AGENT);
        }
        // hsP history store, A-fragment-linear (off critical path, plain cached)
        int rb = s_idx*16 + (t >> 4);
        hsP[(((long)(rb*16 + kt_h))*64 + q_h*16 + (t & 15))*8 + j_h] = hb;
    }
}

// ---------------------------------------------------------------- K3:
// Fused vocab GEMM + per-row softmax partials. BM=128 (was 64), BN=256.
// Halves WvP re-reads (2GB -> 1GB of L2 traffic) at the cost of 2x acc regs.
__global__ __launch_bounds__(256) void vocab_gemm(const unsigned short* __restrict__ hsP,
        const unsigned short* __restrict__ WvP, const float* __restrict__ bvoc,
        const int* __restrict__ captions, float* __restrict__ pmax,
        float* __restrict__ psum, float* __restrict__ tlog){
    int bm = blockIdx.x;    // 0..31 (row-block of 128)
    int bn = blockIdx.y;    // 0..124
    int tid = threadIdx.x;
    int wv = tid >> 6, L = tid & 63;
    int q = L >> 4, ln = L & 15;
    __shared__ int   tgt_s[128];
    __shared__ float wmax_s[4][128], wsum_s[4][128];
    if (tid < 128){
        int rg = bm*128 + tid;
        tgt_s[tid] = captions[(rg >> 8)*257 + (rg & 255) + 1];
    }
    __syncthreads();
    f32x4 acc[8][4];
    for (int mt=0;mt<8;++mt) for (int nt=0;nt<4;++nt) acc[mt][nt] = (f32x4){0.f,0.f,0.f,0.f};
    int colb = bn*256 + wv*64;
    const unsigned short* aB = hsP + ((long)(bm*8)*16)*512;        // rb = bm*8 + mt
    const unsigned short* bB = WvP + ((long)(bn*16 + wv*4)*16)*512; // vb = bn*16+wv*4+nt
    #pragma unroll 2
    for (int kt = 0; kt < 16; ++kt){
        short8 a[8], bb[4];
        #pragma unroll
        for (int mt=0;mt<8;++mt)
            a[mt] = *(const short8*)(aB + ((long)(mt*16 + kt)*64 + L)*8);
        #pragma unroll
        for (int nt=0;nt<4;++nt)
            bb[nt] = *(const short8*)(bB + ((long)(nt*16 + kt)*64 + L)*8);
        #pragma unroll
        for (int mt=0;mt<8;++mt)
            #pragma unroll
            for (int nt=0;nt<4;++nt)
                acc[mt][nt] = __builtin_amdgcn_mfma_f32_16x16x32_bf16(a[mt], bb[nt], acc[mt][nt], 0,0,0);
    }
    float bv[4];
    #pragma unroll
    for (int nt=0;nt<4;++nt) bv[nt] = bvoc[colb + nt*16 + ln];
    #pragma unroll
    for (int mt=0;mt<8;++mt) for (int nt=0;nt<4;++nt) for (int r=0;r<4;++r)
        acc[mt][nt][r] += bv[nt];
    // target-logit grab (exactly one lane grid-wide matches per row)
    #pragma unroll
    for (int mt=0;mt<8;++mt) for (int r=0;r<4;++r){
        int rl = mt*16 + q*4 + r;
        int tg = tgt_s[rl] - colb;
        if (tg >= 0 && tg < 64){
            int nt = tg >> 4;
            if ((tg & 15) == ln) tlog[bm*128 + rl] = acc[mt][nt][r];
        }
    }
    // per-row max & sumexp over this block's 256 cols
    #pragma unroll
    for (int mt=0;mt<8;++mt){
        #pragma unroll
        for (int r=0;r<4;++r){
            float m = fmaxf(fmaxf(acc[mt][0][r],acc[mt][1][r]), fmaxf(acc[mt][2][r],acc[mt][3][r]));
            for (int d=1; d<16; d<<=1) m = fmaxf(m, __shfl_xor(m, d, 16));
            float s = __expf(acc[mt][0][r]-m) + __expf(acc[mt][1][r]-m)
                    + __expf(acc[mt][2][r]-m) + __expf(acc[mt][3][r]-m);
            for (int d=1; d<16; d<<=1) s += __shfl_xor(s, d, 16);
            if (ln == 0){ int rl = mt*16 + q*4 + r; wmax_s[wv][rl] = m; wsum_s[wv][rl] = s; }
        }
    }
    __syncthreads();
    if (tid < 128){
        float M = fmaxf(fmaxf(wmax_s[0][tid],wmax_s[1][tid]), fmaxf(wmax_s[2][tid],wmax_s[3][tid]));
        float S = 0.f;
        for (int ww=0; ww<4; ++ww) S += wsum_s[ww][tid]*__expf(wmax_s[ww][tid]-M);
        pmax[(long)bn*NROWS + bm*128 + tid] = M;
        psum[(long)bn*NROWS + bm*128 + tid] = S;
    }
}

// ---------------------------------------------------------------- K4:
// combine 125 partials per row -> lse -> masked NLL -> loss/N
__global__ __launch_bounds__(256) void reduce_loss(const float* __restrict__ pmax,
        const float* __restrict__ psum, const float* __restrict__ tlog,
        const int* __restrict__ captions, float* __restrict__ out){
    int r = blockIdx.x*256 + threadIdx.x;
    float M = -1e30f;
    for (int p=0;p<NVB;++p) M = fmaxf(M, pmax[(long)p*NROWS + r]);
    float S = 0.f;
    for (int p=0;p<NVB;++p) S += psum[(long)p*NROWS + r]*__expf(pmax[(long)p*NROWS + r]-M);
    float lse = M + logf(S);
    float nll = lse - tlog[r];
    int tok = captions[(r >> 8)*257 + (r & 255) + 1];
    float val = (tok != 0) ? nll : 0.f;
    __shared__ float red[256];
    red[threadIdx.x] = val; __syncthreads();
    for (int s=128; s>0; s>>=1){
        if (threadIdx.x < s) red[threadIdx.x] += red[threadIdx.x+s];
        __syncthreads();
    }
    if (threadIdx.x == 0) atomicAdd(out, red[0] * (1.0f/16.0f));
}

// ---------------------------------------------------------------- launch
extern "C" void kernel_launch(void* const* d_in, const int* in_sizes, int n_in,
                              void* d_out, int out_size, void* d_ws, size_t ws_size,
                              hipStream_t stream){
    const int*   captions = (const int*)  d_in[0];
    const float* Wemb     = (const float*)d_in[1];
    const float* Wx       = (const float*)d_in[2];
    const float* Wh       = (const float*)d_in[3];
    const float* b        = (const float*)d_in[4];
    const float* Wv       = (const float*)d_in[5];
    const float* bvoc     = (const float*)d_in[6];
    const float* h_init   = (const float*)d_in[7];

    char* ws = (char*)d_ws;
    float*          xw   = (float*)         (ws + 0);          // 33554432 B
    unsigned short* WvP  = (unsigned short*)(ws + 33554432);   // 32768000 B
    unsigned short* hsP  = (unsigned short*)(ws + 66322432);   //  4194304 B
    float*          pmax = (float*)         (ws + 70516736);   //  2048000 B
    float*          psum = (float*)         (ws + 72564736);   //  2048000 B
    float*          tlog = (float*)         (ws + 74612736);   //    16384 B
    unsigned short* Whp  = (unsigned short*)(ws + 74629120);   //  2097152 B
    u64*            hx   = (u64*)           (ws + 76726272);   //    65536 B (2 bufs x 4096 u64)

    float* out_f = (float*)d_out;

    (void)hipMemsetAsync(d_out, 0, sizeof(float), stream);

    hipLaunchKernelGGL(prep_all,     dim3(560),        dim3(256), 0, stream,
                       captions, Wemb, Wx, b, xw, Wh, Whp, h_init, hx);
    hipLaunchKernelGGL(lstm_wv,      dim3(NWG+NWVT),   dim3(256), 0, stream,
                       xw, Whp, hx, hsP, Wv, WvP);
    hipLaunchKernelGGL(vocab_gemm,   dim3(32,NVB),     dim3(256), 0, stream,
                       hsP, WvP, bvoc, captions, pmax, psum, tlog);
    hipLaunchKernelGGL(reduce_loss,  dim3(16),         dim3(256), 0, stream,
                       pmax, psum, tlog, captions, out_f);
}

// Round 5
// 1241.162 us; speedup vs baseline: 11.5714x; 1.2360x over previous
//
#include <hip/hip_runtime.h>

#define VOCAB   32000
#define WORDVEC 256
#define HIDDEN  512
#define TSTEPS  256
#define NBATCH  16
#define NROWS   (TSTEPS*NBATCH)   // 4096
#define GATES   (4*HIDDEN)        // 2048
#define NVB     125               // 32000/256
#define NWG     32                // LSTM worker WGs (32 x 16 hidden units)
#define NWVT    4000              // wv_pack tiles (500 x 8)

typedef __attribute__((ext_vector_type(8))) short short8;
typedef __attribute__((ext_vector_type(4))) float f32x4;
typedef unsigned long long u64;

#define AGLOAD(p) __hip_atomic_load((p), __ATOMIC_RELAXED, __HIP_MEMORY_SCOPE_AGENT)

__device__ __forceinline__ unsigned short f2bf(float x){
    union { float f; unsigned int u; } v; v.f = x;
    unsigned int r = v.u + 0x7fffu + ((v.u >> 16) & 1u);
    return (unsigned short)(r >> 16);
}

// ---------------------------------------------------------------- K_prep:
// One launch, three independent jobs selected by blockIdx.x:
//   [0,512)    embed_xw  : xw[r][k] = b[k] + W_embed[tok]@Wx
//   [512,544)  whp_prep  : Wh -> per-WG MFMA-B-fragment bf16 image
//   [544,560)  hg_init   : h_0 -> tagged-pair exchange buffer 0
__global__ __launch_bounds__(256) void prep_all(const int* __restrict__ captions,
        const float* __restrict__ Wemb, const float* __restrict__ Wx,
        const float* __restrict__ b, float* __restrict__ xw,
        const float* __restrict__ Wh, unsigned short* __restrict__ Whp,
        const float* __restrict__ h_init, u64* __restrict__ hx){
    __shared__ float xs[8][WORDVEC];
    __shared__ int toks[8];
    int bid = blockIdx.x;
    int tid = threadIdx.x;
    if (bid < 512){
        // ---------------- embed_xw ----------------
        int r0 = bid * 8;
        if (tid < 8){
            int r = r0 + tid; int t = r >> 4, n = r & 15;
            toks[tid] = captions[n*257 + t];
        }
        __syncthreads();
        for (int i = 0; i < 8; ++i){
            int lin = tid + i*256;
            int ri = lin >> 8, d = lin & 255;
            xs[ri][d] = Wemb[(long)toks[ri]*WORDVEC + d];
        }
        __syncthreads();
        float4 b0 = *(const float4*)(b + tid*4);
        float4 b1 = *(const float4*)(b + 1024 + tid*4);
        float acc[8][8];
        for (int ri = 0; ri < 8; ++ri){
            acc[ri][0]=b0.x; acc[ri][1]=b0.y; acc[ri][2]=b0.z; acc[ri][3]=b0.w;
            acc[ri][4]=b1.x; acc[ri][5]=b1.y; acc[ri][6]=b1.z; acc[ri][7]=b1.w;
        }
        for (int d = 0; d < WORDVEC; ++d){
            float4 w0 = *(const float4*)(Wx + (long)d*GATES + tid*4);
            float4 w1 = *(const float4*)(Wx + (long)d*GATES + 1024 + tid*4);
            #pragma unroll
            for (int ri = 0; ri < 8; ++ri){
                float xv = xs[ri][d];
                acc[ri][0] += xv*w0.x; acc[ri][1] += xv*w0.y;
                acc[ri][2] += xv*w0.z; acc[ri][3] += xv*w0.w;
                acc[ri][4] += xv*w1.x; acc[ri][5] += xv*w1.y;
                acc[ri][6] += xv*w1.z; acc[ri][7] += xv*w1.w;
            }
        }
        for (int ri = 0; ri < 8; ++ri){
            float4 o0 = {acc[ri][0],acc[ri][1],acc[ri][2],acc[ri][3]};
            float4 o1 = {acc[ri][4],acc[ri][5],acc[ri][6],acc[ri][7]};
            *(float4*)(xw + (long)(r0+ri)*GATES + tid*4) = o0;
            *(float4*)(xw + (long)(r0+ri)*GATES + 1024 + tid*4) = o1;
        }
    } else if (bid < 544){
        // ---------------- whp_prep ----------------
        int w = bid - 512;
        for (int item = tid; item < 4096; item += 256){
            int f = item >> 6;          // 0..63
            int L = item & 63;
            int kt = f >> 2, nt = f & 3;
            int q = L >> 4, ln = L & 15;
            int col = nt*HIDDEN + w*16 + ln;   // gate nt, unit w*16+ln
            short8 vvec;
            for (int jj = 0; jj < 8; ++jj){
                int k = kt*32 + q*8 + jj;
                vvec[jj] = (short)f2bf(Wh[(long)k*GATES + col]);
            }
            *(short8*)(Whp + ((long)w*4096 + item)*8) = vvec;
        }
    } else {
        // ---------------- hg_init ----------------
        int p = (bid - 544)*256 + tid;   // 4096 pairs
        int fq = p >> 6;
        int j  = (p & 3) * 2;
        int u0 = (fq>>2)*32 + (fq&3)*8 + j;
        u64 pk = (u64)f2bf(h_init[u0]) | ((u64)f2bf(h_init[u0+1]) << 16);   // tag 0
        hx[p] = pk;
    }
}

// ---------------------------------------------------------------- K2:
// Batched LSTM (verified round-1 protocol: tagged-u64 agent-scope exchange)
// + co-grid wv_pack: blocks >= NWG convert W_vocab tiles while the 32 LSTM
// workers run their latency-bound recurrence on 32 CUs.
__global__ __launch_bounds__(256) void lstm_wv(const float* __restrict__ xw,
        const unsigned short* __restrict__ Whp, u64* __restrict__ hx,
        unsigned short* __restrict__ hsP,
        const float* __restrict__ Wv, unsigned short* __restrict__ WvP){
    __shared__ unsigned int hstage[4096];   // 16 KB (lstm role)
    __shared__ float a_s[4][16][16];        // 4 KB  (lstm role)
    __shared__ float s[64][65];             // 16.6 KB (wv role)
    int tid = threadIdx.x;       // 0..255

    if (blockIdx.x >= NWG){
        // ---------------- wv_pack role ----------------
        int tile = blockIdx.x - NWG;        // 0..3999
        int v0 = (tile >> 3) * 64;          // 500 column-tiles
        int k0 = (tile & 7) * 64;           // 8 row-tiles
        for (int i = 0; i < 16; ++i){
            int lin = tid + i*256;
            int kk = lin >> 6, vv = lin & 63;
            s[kk][vv] = Wv[(long)(k0+kk)*VOCAB + v0 + vv];
        }
        __syncthreads();
        for (int i = 0; i < 2; ++i){
            int lr = tid + i*256;          // 0..511 lane-rows
            int f  = lr >> 6;              // 0..7: vbl(0..3) x ktl(0..1)
            int vbl = f >> 1, ktl = f & 1;
            int L = lr & 63, q = L >> 4, ln = L & 15;
            short8 o;
            #pragma unroll
            for (int j = 0; j < 8; ++j)
                o[j] = (short)f2bf(s[ktl*32 + q*8 + j][vbl*16 + ln]);
            long vb = (long)(tile >> 3)*4 + vbl;
            long kt = (long)(tile & 7)*2 + ktl;
            *(short8*)(WvP + ((vb*16 + kt)*64 + L)*8) = o;
        }
        return;
    }

    // ---------------- lstm role (verified round-1 code) ----------------
    int w = blockIdx.x;          // 0..31
    int wv = tid >> 6;           // wave = gate = N-tile (0..3)
    int L = tid & 63;
    int q = L >> 4, ln = L & 15;
    int s_idx = tid >> 4, jl = tid & 15;   // (sequence, local hidden unit)

    // Wh B-fragments -> registers (wave wv uses fragments kt*4+wv only)
    short8 bw[16];
    #pragma unroll
    for (int kt = 0; kt < 16; ++kt)
        bw[kt] = *(const short8*)(Whp + ((long)w*4096 + (kt*4+wv)*64 + L)*8);

    float c_r = 0.f;
    int fq_pub = (w>>1)*4 + (w&1)*2 + (jl>>3);
    int pubIdx = fq_pub*64 + s_idx*4 + ((jl>>1)&3);
    int kt_h = w >> 1;
    int q_h  = ((w & 1) << 1) | (jl >> 3);
    int j_h  = jl & 7;

    for (int t = 0; t < TSTEPS; ++t){
        // xw loads first: HBM latency overlaps the poll
        long xb = (long)(t*16 + s_idx)*GATES + w*16 + jl;
        float xg0 = xw[xb], xg1 = xw[xb+512], xg2 = xw[xb+1024], xg3 = xw[xb+1536];

        const u64* hr = hx + (t & 1)*4096;
        u64*       hw = hx + ((t+1) & 1)*4096;

        // ---- poll + stage: 16 coalesced u64/thread, spin until all tags == t
        u64 v[16];
        #pragma unroll
        for (int i = 0; i < 16; ++i)
            v[i] = AGLOAD(hr + tid + i*256);
        for (;;){
            u64 bad = 0;
            #pragma unroll
            for (int i = 0; i < 16; ++i) bad |= (v[i] >> 32) ^ (u64)(unsigned)t;
            if (!bad) break;
            #pragma unroll
            for (int i = 0; i < 16; ++i)
                v[i] = AGLOAD(hr + tid + i*256);
        }
        #pragma unroll
        for (int i = 0; i < 16; ++i) hstage[tid + i*256] = (unsigned)v[i];
        __syncthreads();   // S1: stage complete (also orders vs prev a_s reads)

        // ---- MFMA: A-frag (kt,q,ln) = 4 contiguous u32 (linear sweep)
        f32x4 acc = {0.f,0.f,0.f,0.f};
        #pragma unroll
        for (int kt = 0; kt < 16; ++kt){
            short8 a = *(const short8*)((const unsigned short*)hstage + (kt*256 + q*64 + ln*4)*2);
            acc = __builtin_amdgcn_mfma_f32_16x16x32_bf16(a, bw[kt], acc, 0, 0, 0);
        }
        #pragma unroll
        for (int r = 0; r < 4; ++r) a_s[wv][q*4 + r][ln] = acc[r];
        __syncthreads();   // S2: a_s complete (also: all hstage reads done)

        // ---- gate phase
        float ai = a_s[0][s_idx][jl] + xg0;
        float af = a_s[1][s_idx][jl] + xg1;
        float ao = a_s[2][s_idx][jl] + xg2;
        float ag = a_s[3][s_idx][jl] + xg3;
        float ig = 1.f/(1.f + __expf(-ai));
        float fg = 1.f/(1.f + __expf(-af));
        float og = 1.f/(1.f + __expf(-ao));
        float gg = 2.f/(1.f + __expf(-2.f*ag)) - 1.f;
        c_r = fg*c_r + ig*gg;
        float hv = og * (2.f/(1.f + __expf(-2.f*c_r)) - 1.f);
        unsigned short hb = f2bf(hv);

        // ---- publish: pack {tag=t+1 | h[jl+1] | h[jl]}, fire-and-forget
        int hv32 = (int)hb;
        int other = __shfl(hv32, L ^ 1);
        if ((jl & 1) == 0){
            u64 pk = (u64)(unsigned short)hv32
                   | ((u64)(unsigned short)other << 16)
                   | ((u64)(unsigned)(t+1) << 32);
            __hip_atomic_store(hw + pubIdx, pk, __ATOMIC_RELAXED, __HIP_MEMORY_SCOPE_AGENT);
        }
        // hsP history store, A-fragment-linear (off critical path, plain cached)
        int rb = s_idx*16 + (t >> 4);
        hsP[(((long)(rb*16 + kt_h))*64 + q_h*16 + (t & 15))*8 + j_h] = hb;
    }
}

// ---------------------------------------------------------------- K3:
// Fused vocab GEMM + per-row softmax partials. BM=128, BN=256.
// Round 5 fix: __launch_bounds__(256,2) -> VGPR cap 256 (was 152, which
// spilled the 128-VGPR accumulator to scratch: 1.1 GB of HBM writes).
// acc[8][4] (128 VGPR) + operands ~210 VGPR total, 2 blocks/CU.
__global__ __launch_bounds__(256, 2) void vocab_gemm(const unsigned short* __restrict__ hsP,
        const unsigned short* __restrict__ WvP, const float* __restrict__ bvoc,
        const int* __restrict__ captions, float* __restrict__ pmax,
        float* __restrict__ psum, float* __restrict__ tlog){
    int bm = blockIdx.x;    // 0..31 (row-block of 128)
    int bn = blockIdx.y;    // 0..124
    int tid = threadIdx.x;
    int wv = tid >> 6, L = tid & 63;
    int q = L >> 4, ln = L & 15;
    __shared__ int   tgt_s[128];
    __shared__ float wmax_s[4][128], wsum_s[4][128];
    if (tid < 128){
        int rg = bm*128 + tid;
        tgt_s[tid] = captions[(rg >> 8)*257 + (rg & 255) + 1];
    }
    __syncthreads();
    f32x4 acc[8][4];
    for (int mt=0;mt<8;++mt) for (int nt=0;nt<4;++nt) acc[mt][nt] = (f32x4){0.f,0.f,0.f,0.f};
    int colb = bn*256 + wv*64;
    const unsigned short* aB = hsP + ((long)(bm*8)*16)*512;        // rb = bm*8 + mt
    const unsigned short* bB = WvP + ((long)(bn*16 + wv*4)*16)*512; // vb = bn*16+wv*4+nt
    #pragma unroll 2
    for (int kt = 0; kt < 16; ++kt){
        short8 a[8], bb[4];
        #pragma unroll
        for (int mt=0;mt<8;++mt)
            a[mt] = *(const short8*)(aB + ((long)(mt*16 + kt)*64 + L)*8);
        #pragma unroll
        for (int nt=0;nt<4;++nt)
            bb[nt] = *(const short8*)(bB + ((long)(nt*16 + kt)*64 + L)*8);
        #pragma unroll
        for (int mt=0;mt<8;++mt)
            #pragma unroll
            for (int nt=0;nt<4;++nt)
                acc[mt][nt] = __builtin_amdgcn_mfma_f32_16x16x32_bf16(a[mt], bb[nt], acc[mt][nt], 0,0,0);
    }
    float bv[4];
    #pragma unroll
    for (int nt=0;nt<4;++nt) bv[nt] = bvoc[colb + nt*16 + ln];
    #pragma unroll
    for (int mt=0;mt<8;++mt) for (int nt=0;nt<4;++nt) for (int r=0;r<4;++r)
        acc[mt][nt][r] += bv[nt];
    // target-logit grab (exactly one lane grid-wide matches per row)
    #pragma unroll
    for (int mt=0;mt<8;++mt) for (int r=0;r<4;++r){
        int rl = mt*16 + q*4 + r;
        int tg = tgt_s[rl] - colb;
        if (tg >= 0 && tg < 64){
            int nt = tg >> 4;
            if ((tg & 15) == ln) tlog[bm*128 + rl] = acc[mt][nt][r];
        }
    }
    // per-row max & sumexp over this block's 256 cols
    #pragma unroll
    for (int mt=0;mt<8;++mt){
        #pragma unroll
        for (int r=0;r<4;++r){
            float m = fmaxf(fmaxf(acc[mt][0][r],acc[mt][1][r]), fmaxf(acc[mt][2][r],acc[mt][3][r]));
            for (int d=1; d<16; d<<=1) m = fmaxf(m, __shfl_xor(m, d, 16));
            float s = __expf(acc[mt][0][r]-m) + __expf(acc[mt][1][r]-m)
                    + __expf(acc[mt][2][r]-m) + __expf(acc[mt][3][r]-m);
            for (int d=1; d<16; d<<=1) s += __shfl_xor(s, d, 16);
            if (ln == 0){ int rl = mt*16 + q*4 + r; wmax_s[wv][rl] = m; wsum_s[wv][rl] = s; }
        }
    }
    __syncthreads();
    if (tid < 128){
        float M = fmaxf(fmaxf(wmax_s[0][tid],wmax_s[1][tid]), fmaxf(wmax_s[2][tid],wmax_s[3][tid]));
        float S = 0.f;
        for (int ww=0; ww<4; ++ww) S += wsum_s[ww][tid]*__expf(wmax_s[ww][tid]-M);
        pmax[(long)bn*NROWS + bm*128 + tid] = M;
        psum[(long)bn*NROWS + bm*128 + tid] = S;
    }
}

// ---------------------------------------------------------------- K4:
// combine 125 partials per row -> lse -> masked NLL -> loss/N
__global__ __launch_bounds__(256) void reduce_loss(const float* __restrict__ pmax,
        const float* __restrict__ psum, const float* __restrict__ tlog,
        const int* __restrict__ captions, float* __restrict__ out){
    int r = blockIdx.x*256 + threadIdx.x;
    float M = -1e30f;
    for (int p=0;p<NVB;++p) M = fmaxf(M, pmax[(long)p*NROWS + r]);
    float S = 0.f;
    for (int p=0;p<NVB;++p) S += psum[(long)p*NROWS + r]*__expf(pmax[(long)p*NROWS + r]-M);
    float lse = M + logf(S);
    float nll = lse - tlog[r];
    int tok = captions[(r >> 8)*257 + (r & 255) + 1];
    float val = (tok != 0) ? nll : 0.f;
    __shared__ float red[256];
    red[threadIdx.x] = val; __syncthreads();
    for (int s=128; s>0; s>>=1){
        if (threadIdx.x < s) red[threadIdx.x] += red[threadIdx.x+s];
        __syncthreads();
    }
    if (threadIdx.x == 0) atomicAdd(out, red[0] * (1.0f/16.0f));
}

// ---------------------------------------------------------------- launch
extern "C" void kernel_launch(void* const* d_in, const int* in_sizes, int n_in,
                              void* d_out, int out_size, void* d_ws, size_t ws_size,
                              hipStream_t stream){
    const int*   captions = (const int*)  d_in[0];
    const float* Wemb     = (const float*)d_in[1];
    const float* Wx       = (const float*)d_in[2];
    const float* Wh       = (const float*)d_in[3];
    const float* b        = (const float*)d_in[4];
    const float* Wv       = (const float*)d_in[5];
    const float* bvoc     = (const float*)d_in[6];
    const float* h_init   = (const float*)d_in[7];

    char* ws = (char*)d_ws;
    float*          xw   = (float*)         (ws + 0);          // 33554432 B
    unsigned short* WvP  = (unsigned short*)(ws + 33554432);   // 32768000 B
    unsigned short* hsP  = (unsigned short*)(ws + 66322432);   //  4194304 B
    float*          pmax = (float*)         (ws + 70516736);   //  2048000 B
    float*          psum = (float*)         (ws + 72564736);   //  2048000 B
    float*          tlog = (float*)         (ws + 74612736);   //    16384 B
    unsigned short* Whp  = (unsigned short*)(ws + 74629120);   //  2097152 B
    u64*            hx   = (u64*)           (ws + 76726272);   //    65536 B (2 bufs x 4096 u64)

    float* out_f = (float*)d_out;

    (void)hipMemsetAsync(d_out, 0, sizeof(float), stream);

    hipLaunchKernelGGL(prep_all,     dim3(560),        dim3(256), 0, stream,
                       captions, Wemb, Wx, b, xw, Wh, Whp, h_init, hx);
    hipLaunchKernelGGL(lstm_wv,      dim3(NWG+NWVT),   dim3(256), 0, stream,
                       xw, Whp, hx, hsP, Wv, WvP);
    hipLaunchKernelGGL(vocab_gemm,   dim3(32,NVB),     dim3(256), 0, stream,
                       hsP, WvP, bvoc, captions, pmax, psum, tlog);
    hipLaunchKernelGGL(reduce_loss,  dim3(16),         dim3(256), 0, stream,
                       pmax, psum, tlog, captions, out_f);
}

// Round 6
// 1168.916 us; speedup vs baseline: 12.2866x; 1.0618x over previous
//
#include <hip/hip_runtime.h>

#define VOCAB   32000
#define WORDVEC 256
#define HIDDEN  512
#define TSTEPS  256
#define NBATCH  16
#define NROWS   (TSTEPS*NBATCH)   // 4096
#define GATES   (4*HIDDEN)        // 2048
#define NVB     125               // 32000/256
#define NWG     32                // LSTM worker WGs (32 x 16 hidden units)
#define NVBLK   8000              // vocab blocks (64 bm x 125 bn)
#define SPINCAP (1<<16)           // bounded readiness spin (escape hatch)

typedef __attribute__((ext_vector_type(8))) short short8;
typedef __attribute__((ext_vector_type(4))) float f32x4;
typedef unsigned long long u64;

#define AGLOAD(p) __hip_atomic_load((p), __ATOMIC_RELAXED, __HIP_MEMORY_SCOPE_AGENT)

__device__ __forceinline__ unsigned short f2bf(float x){
    union { float f; unsigned int u; } v; v.f = x;
    unsigned int r = v.u + 0x7fffu + ((v.u >> 16) & 1u);
    return (unsigned short)(r >> 16);
}

// ---------------------------------------------------------------- K_prep:
// One launch, four independent jobs selected by blockIdx.x:
//   [0,512)     embed_xw : xw[r][k] = b[k] + W_embed[tok]@Wx
//   [512,544)   whp_prep : Wh -> per-WG MFMA-B-fragment bf16 image
//   [544,560)   hg_init  : h_0 -> tagged-pair exchange buffer 0 (+prog=0)
//   [560,4560)  wv_pack  : W_vocab -> MFMA-B-fragment-linear bf16
__global__ __launch_bounds__(256) void prep_all(const int* __restrict__ captions,
        const float* __restrict__ Wemb, const float* __restrict__ Wx,
        const float* __restrict__ b, float* __restrict__ xw,
        const float* __restrict__ Wh, unsigned short* __restrict__ Whp,
        const float* __restrict__ h_init, u64* __restrict__ hx,
        const float* __restrict__ Wv, unsigned short* __restrict__ WvP,
        int* __restrict__ prog){
    __shared__ float s[64][65];    // wv role (16.6 KB) -- also covers xs (8 KB)
    float (*xs)[WORDVEC] = (float(*)[WORDVEC])s;
    __shared__ int toks[8];
    int bid = blockIdx.x;
    int tid = threadIdx.x;
    if (bid < 512){
        // ---------------- embed_xw ----------------
        int r0 = bid * 8;
        if (tid < 8){
            int r = r0 + tid; int t = r >> 4, n = r & 15;
            toks[tid] = captions[n*257 + t];
        }
        __syncthreads();
        for (int i = 0; i < 8; ++i){
            int lin = tid + i*256;
            int ri = lin >> 8, d = lin & 255;
            xs[ri][d] = Wemb[(long)toks[ri]*WORDVEC + d];
        }
        __syncthreads();
        float4 b0 = *(const float4*)(b + tid*4);
        float4 b1 = *(const float4*)(b + 1024 + tid*4);
        float acc[8][8];
        for (int ri = 0; ri < 8; ++ri){
            acc[ri][0]=b0.x; acc[ri][1]=b0.y; acc[ri][2]=b0.z; acc[ri][3]=b0.w;
            acc[ri][4]=b1.x; acc[ri][5]=b1.y; acc[ri][6]=b1.z; acc[ri][7]=b1.w;
        }
        for (int d = 0; d < WORDVEC; ++d){
            float4 w0 = *(const float4*)(Wx + (long)d*GATES + tid*4);
            float4 w1 = *(const float4*)(Wx + (long)d*GATES + 1024 + tid*4);
            #pragma unroll
            for (int ri = 0; ri < 8; ++ri){
                float xv = xs[ri][d];
                acc[ri][0] += xv*w0.x; acc[ri][1] += xv*w0.y;
                acc[ri][2] += xv*w0.z; acc[ri][3] += xv*w0.w;
                acc[ri][4] += xv*w1.x; acc[ri][5] += xv*w1.y;
                acc[ri][6] += xv*w1.z; acc[ri][7] += xv*w1.w;
            }
        }
        for (int ri = 0; ri < 8; ++ri){
            float4 o0 = {acc[ri][0],acc[ri][1],acc[ri][2],acc[ri][3]};
            float4 o1 = {acc[ri][4],acc[ri][5],acc[ri][6],acc[ri][7]};
            *(float4*)(xw + (long)(r0+ri)*GATES + tid*4) = o0;
            *(float4*)(xw + (long)(r0+ri)*GATES + 1024 + tid*4) = o1;
        }
    } else if (bid < 544){
        // ---------------- whp_prep ----------------
        int w = bid - 512;
        for (int item = tid; item < 4096; item += 256){
            int f = item >> 6;          // 0..63
            int L = item & 63;
            int kt = f >> 2, nt = f & 3;
            int q = L >> 4, ln = L & 15;
            int col = nt*HIDDEN + w*16 + ln;   // gate nt, unit w*16+ln
            short8 vvec;
            for (int jj = 0; jj < 8; ++jj){
                int k = kt*32 + q*8 + jj;
                vvec[jj] = (short)f2bf(Wh[(long)k*GATES + col]);
            }
            *(short8*)(Whp + ((long)w*4096 + item)*8) = vvec;
        }
    } else if (bid < 560){
        // ---------------- hg_init (+ progress zero) ----------------
        if (bid == 544 && tid < 32) prog[tid] = 0;
        int p = (bid - 544)*256 + tid;   // 4096 pairs
        int fq = p >> 6;
        int j  = (p & 3) * 2;
        int u0 = (fq>>2)*32 + (fq&3)*8 + j;
        u64 pk = (u64)f2bf(h_init[u0]) | ((u64)f2bf(h_init[u0+1]) << 16);   // tag 0
        hx[p] = pk;
    } else {
        // ---------------- wv_pack ----------------
        int tile = bid - 560;               // 0..3999
        int v0 = (tile >> 3) * 64;          // 500 column-tiles
        int k0 = (tile & 7) * 64;           // 8 row-tiles
        for (int i = 0; i < 16; ++i){
            int lin = tid + i*256;
            int kk = lin >> 6, vv = lin & 63;
            s[kk][vv] = Wv[(long)(k0+kk)*VOCAB + v0 + vv];
        }
        __syncthreads();
        for (int i = 0; i < 2; ++i){
            int lr = tid + i*256;          // 0..511 lane-rows
            int f  = lr >> 6;              // 0..7: vbl(0..3) x ktl(0..1)
            int vbl = f >> 1, ktl = f & 1;
            int L = lr & 63, q = L >> 4, ln = L & 15;
            short8 o;
            #pragma unroll
            for (int j = 0; j < 8; ++j)
                o[j] = (short)f2bf(s[ktl*32 + q*8 + j][vbl*16 + ln]);
            long vb = (long)(tile >> 3)*4 + vbl;
            long kt = (long)(tile & 7)*2 + ktl;
            *(short8*)(WvP + ((vb*16 + kt)*64 + L)*8) = o;
        }
    }
}

// ---------------------------------------------------------------- K2:
// Fused LSTM + vocab GEMM.
//   blocks [0,32):      verified LSTM recurrence (tagged-u64 agent exchange),
//                       hsP now published via agent-scope u32 pair-stores;
//                       every 16 steps: vmcnt drain + barrier + prog[w]=chunk.
//   blocks [32,8032):   vocab GEMM (BM=64, BN=256, verified shape), ordered by
//                       readiness group; spin on prog[] until their hsP rows
//                       are final, then compute. Overlaps the LSTM's idle CUs.
__global__ __launch_bounds__(256, 2) void lstm_vocab(const float* __restrict__ xw,
        const unsigned short* __restrict__ Whp, u64* __restrict__ hx,
        unsigned short* __restrict__ hsP, int* __restrict__ prog,
        const unsigned short* __restrict__ WvP, const float* __restrict__ bvoc,
        const int* __restrict__ captions, float* __restrict__ pmax,
        float* __restrict__ psum, float* __restrict__ tlog){
    __shared__ unsigned int hstage[4096];   // 16 KB (lstm role)
    __shared__ float a_s[4][16][16];        // 4 KB  (lstm role)
    __shared__ int   tgt_s[64];             // vocab role
    __shared__ float wmax_s[4][64], wsum_s[4][64];
    int tid = threadIdx.x;       // 0..255

    if (blockIdx.x >= NWG){
        // ================= vocab role =================
        int vid = blockIdx.x - NWG;         // 0..7999
        int pri = vid / 2000;               // readiness group: needs chunks 4*(pri+1)
        int idx = vid % 2000;
        int bn  = idx % 125;
        int bm  = (idx / 125) * 4 + pri;    // bm&3 == pri
        int need = (pri + 1) * 4;           // lstm chunks (16 steps each) required

        if (tid == 0){
            int cnt = 0;
            for (;;){
                int mn = 1 << 30;
                for (int i = 0; i < 32; ++i){
                    int p = AGLOAD(&prog[i]);
                    mn = p < mn ? p : mn;
                }
                if (mn >= need) break;
                __builtin_amdgcn_s_sleep(32);
                if (++cnt > SPINCAP) break;   // escape hatch (never in practice)
            }
        }
        __syncthreads();

        int wv = tid >> 6, L = tid & 63;
        int q = L >> 4, ln = L & 15;
        if (tid < 64){
            int rg = bm*64 + tid;
            tgt_s[tid] = captions[(rg >> 8)*257 + (rg & 255) + 1];
        }
        __syncthreads();
        f32x4 acc[4][4];
        for (int mt=0;mt<4;++mt) for (int nt=0;nt<4;++nt) acc[mt][nt] = (f32x4){0.f,0.f,0.f,0.f};
        int colb = bn*256 + wv*64;
        const unsigned short* aB = hsP + ((long)(bm*4)*16)*512;        // rb = bm*4 + mt
        const unsigned short* bB = WvP + ((long)(bn*16 + wv*4)*16)*512; // vb = bn*16+wv*4+nt
        #pragma unroll 4
        for (int kt = 0; kt < 16; ++kt){
            short8 a[4], bb[4];
            #pragma unroll
            for (int mt=0;mt<4;++mt)
                a[mt] = *(const short8*)(aB + ((long)(mt*16 + kt)*64 + L)*8);
            #pragma unroll
            for (int nt=0;nt<4;++nt)
                bb[nt] = *(const short8*)(bB + ((long)(nt*16 + kt)*64 + L)*8);
            #pragma unroll
            for (int mt=0;mt<4;++mt)
                #pragma unroll
                for (int nt=0;nt<4;++nt)
                    acc[mt][nt] = __builtin_amdgcn_mfma_f32_16x16x32_bf16(a[mt], bb[nt], acc[mt][nt], 0,0,0);
        }
        float bv[4];
        #pragma unroll
        for (int nt=0;nt<4;++nt) bv[nt] = bvoc[colb + nt*16 + ln];
        #pragma unroll
        for (int mt=0;mt<4;++mt) for (int nt=0;nt<4;++nt) for (int r=0;r<4;++r)
            acc[mt][nt][r] += bv[nt];
        // target-logit grab (exactly one lane grid-wide matches per row)
        #pragma unroll
        for (int mt=0;mt<4;++mt) for (int r=0;r<4;++r){
            int rl = mt*16 + q*4 + r;
            int tg = tgt_s[rl] - colb;
            if (tg >= 0 && tg < 64){
                int nt = tg >> 4;
                if ((tg & 15) == ln) tlog[bm*64 + rl] = acc[mt][nt][r];
            }
        }
        // per-row max & sumexp over this block's 256 cols
        #pragma unroll
        for (int mt=0;mt<4;++mt){
            #pragma unroll
            for (int r=0;r<4;++r){
                float m = fmaxf(fmaxf(acc[mt][0][r],acc[mt][1][r]), fmaxf(acc[mt][2][r],acc[mt][3][r]));
                for (int d=1; d<16; d<<=1) m = fmaxf(m, __shfl_xor(m, d, 16));
                float s = __expf(acc[mt][0][r]-m) + __expf(acc[mt][1][r]-m)
                        + __expf(acc[mt][2][r]-m) + __expf(acc[mt][3][r]-m);
                for (int d=1; d<16; d<<=1) s += __shfl_xor(s, d, 16);
                if (ln == 0){ int rl = mt*16 + q*4 + r; wmax_s[wv][rl] = m; wsum_s[wv][rl] = s; }
            }
        }
        __syncthreads();
        if (tid < 64){
            float M = fmaxf(fmaxf(wmax_s[0][tid],wmax_s[1][tid]), fmaxf(wmax_s[2][tid],wmax_s[3][tid]));
            float S = 0.f;
            for (int ww=0; ww<4; ++ww) S += wsum_s[ww][tid]*__expf(wmax_s[ww][tid]-M);
            pmax[(long)bn*NROWS + bm*64 + tid] = M;
            psum[(long)bn*NROWS + bm*64 + tid] = S;
        }
        return;
    }

    // ================= lstm role (verified round-1 protocol) =================
    int w = blockIdx.x;          // 0..31
    int wv = tid >> 6;           // wave = gate = N-tile (0..3)
    int L = tid & 63;
    int q = L >> 4, ln = L & 15;
    int s_idx = tid >> 4, jl = tid & 15;   // (sequence, local hidden unit)

    // Wh B-fragments -> registers (wave wv uses fragments kt*4+wv only)
    short8 bw[16];
    #pragma unroll
    for (int kt = 0; kt < 16; ++kt)
        bw[kt] = *(const short8*)(Whp + ((long)w*4096 + (kt*4+wv)*64 + L)*8);

    float c_r = 0.f;
    int fq_pub = (w>>1)*4 + (w&1)*2 + (jl>>3);
    int pubIdx = fq_pub*64 + s_idx*4 + ((jl>>1)&3);
    int kt_h = w >> 1;
    int q_h  = ((w & 1) << 1) | (jl >> 3);
    int j_h  = jl & 7;
    unsigned int* hsP32 = (unsigned int*)hsP;

    for (int t = 0; t < TSTEPS; ++t){
        // xw loads first: HBM latency overlaps the poll
        long xb = (long)(t*16 + s_idx)*GATES + w*16 + jl;
        float xg0 = xw[xb], xg1 = xw[xb+512], xg2 = xw[xb+1024], xg3 = xw[xb+1536];

        const u64* hr = hx + (t & 1)*4096;
        u64*       hw = hx + ((t+1) & 1)*4096;

        // ---- poll + stage: 16 coalesced u64/thread, spin until all tags == t
        u64 v[16];
        #pragma unroll
        for (int i = 0; i < 16; ++i)
            v[i] = AGLOAD(hr + tid + i*256);
        for (;;){
            u64 bad = 0;
            #pragma unroll
            for (int i = 0; i < 16; ++i) bad |= (v[i] >> 32) ^ (u64)(unsigned)t;
            if (!bad) break;
            #pragma unroll
            for (int i = 0; i < 16; ++i)
                v[i] = AGLOAD(hr + tid + i*256);
        }
        #pragma unroll
        for (int i = 0; i < 16; ++i) hstage[tid + i*256] = (unsigned)v[i];
        __syncthreads();   // S1: stage complete (also orders vs prev a_s reads)

        // ---- MFMA: A-frag (kt,q,ln) = 4 contiguous u32 (linear sweep)
        f32x4 acc = {0.f,0.f,0.f,0.f};
        #pragma unroll
        for (int kt = 0; kt < 16; ++kt){
            short8 a = *(const short8*)((const unsigned short*)hstage + (kt*256 + q*64 + ln*4)*2);
            acc = __builtin_amdgcn_mfma_f32_16x16x32_bf16(a, bw[kt], acc, 0, 0, 0);
        }
        #pragma unroll
        for (int r = 0; r < 4; ++r) a_s[wv][q*4 + r][ln] = acc[r];
        __syncthreads();   // S2: a_s complete (also: all hstage reads done)

        // ---- gate phase
        float ai = a_s[0][s_idx][jl] + xg0;
        float af = a_s[1][s_idx][jl] + xg1;
        float ao = a_s[2][s_idx][jl] + xg2;
        float ag = a_s[3][s_idx][jl] + xg3;
        float ig = 1.f/(1.f + __expf(-ai));
        float fg = 1.f/(1.f + __expf(-af));
        float og = 1.f/(1.f + __expf(-ao));
        float gg = 2.f/(1.f + __expf(-2.f*ag)) - 1.f;
        c_r = fg*c_r + ig*gg;
        float hv = og * (2.f/(1.f + __expf(-2.f*c_r)) - 1.f);
        unsigned short hb = f2bf(hv);

        // ---- publish h (tagged u64) + hsP (agent u32 pair), fire-and-forget
        int hv32 = (int)hb;
        int other = __shfl(hv32, L ^ 1);
        int rb = s_idx*16 + (t >> 4);
        if ((jl & 1) == 0){
            u64 pk = (u64)(unsigned short)hv32
                   | ((u64)(unsigned short)other << 16)
                   | ((u64)(unsigned)(t+1) << 32);
            __hip_atomic_store(hw + pubIdx, pk, __ATOMIC_RELAXED, __HIP_MEMORY_SCOPE_AGENT);
            unsigned int hp = (unsigned int)(unsigned short)hv32
                            | ((unsigned int)(unsigned short)other << 16);
            // u32 index = u16 index / 2 (j_h is even here)
            __hip_atomic_store(hsP32 + (((long)(rb*16 + kt_h))*64 + q_h*16 + (t & 15))*4 + (j_h >> 1),
                               hp, __ATOMIC_RELAXED, __HIP_MEMORY_SCOPE_AGENT);
        }
        // ---- chunk boundary: drain stores, then publish progress
        if ((t & 15) == 15){
            asm volatile("s_waitcnt vmcnt(0)" ::: "memory");
            __syncthreads();
            if (tid == 0)
                __hip_atomic_store(&prog[w], (t >> 4) + 1, __ATOMIC_RELAXED, __HIP_MEMORY_SCOPE_AGENT);
        }
    }
}

// ---------------------------------------------------------------- K4:
// combine 125 partials per row -> lse -> masked NLL -> loss/N
__global__ __launch_bounds__(256) void reduce_loss(const float* __restrict__ pmax,
        const float* __restrict__ psum, const float* __restrict__ tlog,
        const int* __restrict__ captions, float* __restrict__ out){
    int r = blockIdx.x*256 + threadIdx.x;
    float M = -1e30f;
    for (int p=0;p<NVB;++p) M = fmaxf(M, pmax[(long)p*NROWS + r]);
    float S = 0.f;
    for (int p=0;p<NVB;++p) S += psum[(long)p*NROWS + r]*__expf(pmax[(long)p*NROWS + r]-M);
    float lse = M + logf(S);
    float nll = lse - tlog[r];
    int tok = captions[(r >> 8)*257 + (r & 255) + 1];
    float val = (tok != 0) ? nll : 0.f;
    __shared__ float red[256];
    red[threadIdx.x] = val; __syncthreads();
    for (int s=128; s>0; s>>=1){
        if (threadIdx.x < s) red[threadIdx.x] += red[threadIdx.x+s];
        __syncthreads();
    }
    if (threadIdx.x == 0) atomicAdd(out, red[0] * (1.0f/16.0f));
}

// ---------------------------------------------------------------- launch
extern "C" void kernel_launch(void* const* d_in, const int* in_sizes, int n_in,
                              void* d_out, int out_size, void* d_ws, size_t ws_size,
                              hipStream_t stream){
    const int*   captions = (const int*)  d_in[0];
    const float* Wemb     = (const float*)d_in[1];
    const float* Wx       = (const float*)d_in[2];
    const float* Wh       = (const float*)d_in[3];
    const float* b        = (const float*)d_in[4];
    const float* Wv       = (const float*)d_in[5];
    const float* bvoc     = (const float*)d_in[6];
    const float* h_init   = (const float*)d_in[7];

    char* ws = (char*)d_ws;
    float*          xw   = (float*)         (ws + 0);          // 33554432 B
    unsigned short* WvP  = (unsigned short*)(ws + 33554432);   // 32768000 B
    unsigned short* hsP  = (unsigned short*)(ws + 66322432);   //  4194304 B
    float*          pmax = (float*)         (ws + 70516736);   //  2048000 B
    float*          psum = (float*)         (ws + 72564736);   //  2048000 B
    float*          tlog = (float*)         (ws + 74612736);   //    16384 B
    unsigned short* Whp  = (unsigned short*)(ws + 74629120);   //  2097152 B
    u64*            hx   = (u64*)           (ws + 76726272);   //    65536 B (2 bufs x 4096 u64)
    int*            prog = (int*)           (ws + 76791808);   //      128 B (32 progress ctrs)

    float* out_f = (float*)d_out;

    (void)hipMemsetAsync(d_out, 0, sizeof(float), stream);

    hipLaunchKernelGGL(prep_all,    dim3(4560),       dim3(256), 0, stream,
                       captions, Wemb, Wx, b, xw, Wh, Whp, h_init, hx, Wv, WvP, prog);
    hipLaunchKernelGGL(lstm_vocab,  dim3(NWG+NVBLK),  dim3(256), 0, stream,
                       xw, Whp, hx, hsP, prog, WvP, bvoc, captions, pmax, psum, tlog);
    hipLaunchKernelGGL(reduce_loss, dim3(16),         dim3(256), 0, stream,
                       pmax, psum, tlog, captions, out_f);
}

// Round 7
// 1059.922 us; speedup vs baseline: 13.5501x; 1.1028x over previous
//
#include <hip/hip_runtime.h>

#define VOCAB   32000
#define WORDVEC 256
#define HIDDEN  512
#define TSTEPS  256
#define NBATCH  16
#define NROWS   (TSTEPS*NBATCH)   // 4096
#define GATES   (4*HIDDEN)        // 2048
#define NVB     125               // 32000/256
#define NWG     32                // LSTM worker WGs (32 x 16 hidden units)
#define NVBLK   8000              // vocab blocks (64 bm x 125 bn)
#define SPINCAP (1<<16)           // bounded readiness spin (escape hatch)

typedef __attribute__((ext_vector_type(8))) short short8;
typedef __attribute__((ext_vector_type(4))) float f32x4;
typedef unsigned long long u64;

#define AGLOAD(p) __hip_atomic_load((p), __ATOMIC_RELAXED, __HIP_MEMORY_SCOPE_AGENT)

__device__ __forceinline__ unsigned short f2bf(float x){
    union { float f; unsigned int u; } v; v.f = x;
    unsigned int r = v.u + 0x7fffu + ((v.u >> 16) & 1u);
    return (unsigned short)(r >> 16);
}

// ---------------------------------------------------------------- K_prep:
// One launch, four independent jobs selected by blockIdx.x:
//   [0,512)     embed_xw : xw[r][k] = b[k] + W_embed[tok]@Wx
//   [512,544)   whp_prep : Wh -> per-WG MFMA-B-fragment bf16 image
//   [544,560)   hg_init  : h_0 -> tagged-pair exchange buffer 0 (+prog=0)
//   [560,4560)  wv_pack  : W_vocab -> MFMA-B-fragment-linear bf16
__global__ __launch_bounds__(256) void prep_all(const int* __restrict__ captions,
        const float* __restrict__ Wemb, const float* __restrict__ Wx,
        const float* __restrict__ b, float* __restrict__ xw,
        const float* __restrict__ Wh, unsigned short* __restrict__ Whp,
        const float* __restrict__ h_init, u64* __restrict__ hx,
        const float* __restrict__ Wv, unsigned short* __restrict__ WvP,
        int* __restrict__ prog){
    __shared__ float s[64][65];    // wv role (16.6 KB) -- also covers xs (8 KB)
    float (*xs)[WORDVEC] = (float(*)[WORDVEC])s;
    __shared__ int toks[8];
    int bid = blockIdx.x;
    int tid = threadIdx.x;
    if (bid < 512){
        // ---------------- embed_xw ----------------
        int r0 = bid * 8;
        if (tid < 8){
            int r = r0 + tid; int t = r >> 4, n = r & 15;
            toks[tid] = captions[n*257 + t];
        }
        __syncthreads();
        for (int i = 0; i < 8; ++i){
            int lin = tid + i*256;
            int ri = lin >> 8, d = lin & 255;
            xs[ri][d] = Wemb[(long)toks[ri]*WORDVEC + d];
        }
        __syncthreads();
        float4 b0 = *(const float4*)(b + tid*4);
        float4 b1 = *(const float4*)(b + 1024 + tid*4);
        float acc[8][8];
        for (int ri = 0; ri < 8; ++ri){
            acc[ri][0]=b0.x; acc[ri][1]=b0.y; acc[ri][2]=b0.z; acc[ri][3]=b0.w;
            acc[ri][4]=b1.x; acc[ri][5]=b1.y; acc[ri][6]=b1.z; acc[ri][7]=b1.w;
        }
        for (int d = 0; d < WORDVEC; ++d){
            float4 w0 = *(const float4*)(Wx + (long)d*GATES + tid*4);
            float4 w1 = *(const float4*)(Wx + (long)d*GATES + 1024 + tid*4);
            #pragma unroll
            for (int ri = 0; ri < 8; ++ri){
                float xv = xs[ri][d];
                acc[ri][0] += xv*w0.x; acc[ri][1] += xv*w0.y;
                acc[ri][2] += xv*w0.z; acc[ri][3] += xv*w0.w;
                acc[ri][4] += xv*w1.x; acc[ri][5] += xv*w1.y;
                acc[ri][6] += xv*w1.z; acc[ri][7] += xv*w1.w;
            }
        }
        for (int ri = 0; ri < 8; ++ri){
            float4 o0 = {acc[ri][0],acc[ri][1],acc[ri][2],acc[ri][3]};
            float4 o1 = {acc[ri][4],acc[ri][5],acc[ri][6],acc[ri][7]};
            *(float4*)(xw + (long)(r0+ri)*GATES + tid*4) = o0;
            *(float4*)(xw + (long)(r0+ri)*GATES + 1024 + tid*4) = o1;
        }
    } else if (bid < 544){
        // ---------------- whp_prep ----------------
        int w = bid - 512;
        for (int item = tid; item < 4096; item += 256){
            int f = item >> 6;          // 0..63
            int L = item & 63;
            int kt = f >> 2, nt = f & 3;
            int q = L >> 4, ln = L & 15;
            int col = nt*HIDDEN + w*16 + ln;   // gate nt, unit w*16+ln
            short8 vvec;
            for (int jj = 0; jj < 8; ++jj){
                int k = kt*32 + q*8 + jj;
                vvec[jj] = (short)f2bf(Wh[(long)k*GATES + col]);
            }
            *(short8*)(Whp + ((long)w*4096 + item)*8) = vvec;
        }
    } else if (bid < 560){
        // ---------------- hg_init (+ progress zero) ----------------
        if (bid == 544 && tid < 32) prog[tid] = 0;
        int p = (bid - 544)*256 + tid;   // 4096 pairs
        int fq = p >> 6;
        int j  = (p & 3) * 2;
        int u0 = (fq>>2)*32 + (fq&3)*8 + j;
        u64 pk = (u64)f2bf(h_init[u0]) | ((u64)f2bf(h_init[u0+1]) << 16);   // tag 0
        hx[p] = pk;
    } else {
        // ---------------- wv_pack ----------------
        int tile = bid - 560;               // 0..3999
        int v0 = (tile >> 3) * 64;          // 500 column-tiles
        int k0 = (tile & 7) * 64;           // 8 row-tiles
        for (int i = 0; i < 16; ++i){
            int lin = tid + i*256;
            int kk = lin >> 6, vv = lin & 63;
            s[kk][vv] = Wv[(long)(k0+kk)*VOCAB + v0 + vv];
        }
        __syncthreads();
        for (int i = 0; i < 2; ++i){
            int lr = tid + i*256;          // 0..511 lane-rows
            int f  = lr >> 6;              // 0..7: vbl(0..3) x ktl(0..1)
            int vbl = f >> 1, ktl = f & 1;
            int L = lr & 63, q = L >> 4, ln = L & 15;
            short8 o;
            #pragma unroll
            for (int j = 0; j < 8; ++j)
                o[j] = (short)f2bf(s[ktl*32 + q*8 + j][vbl*16 + ln]);
            long vb = (long)(tile >> 3)*4 + vbl;
            long kt = (long)(tile & 7)*2 + ktl;
            *(short8*)(WvP + ((vb*16 + kt)*64 + L)*8) = o;
        }
    }
}

// ---------------------------------------------------------------- K2:
// Fused LSTM + vocab GEMM.
//   blocks [0,32):      verified LSTM recurrence (tagged-u64 agent exchange);
//                       hsP published via agent-scope u32 pair-stores;
//                       every 16 steps: vmcnt drain + barrier + prog[w]=chunk.
//   blocks [32,8032):   vocab GEMM (BM=64, BN=256), ordered by readiness group
//                       with bm-FASTEST inside each group (16 siblings share
//                       one 256KB WvP slice -> L2 reuse). Spin on prog[].
// Register budget pinned with amdgpu_waves_per_eu(2,2): min=2 caps VGPR at
// 256 (vocab role needs ~130 live; round-6's heuristic 92-reg allocation
// spilled it: 816 MB scratch writes), max=2 stops the occupancy heuristic.
__global__ __attribute__((amdgpu_flat_work_group_size(256,256), amdgpu_waves_per_eu(2,2)))
void lstm_vocab(const float* __restrict__ xw,
        const unsigned short* __restrict__ Whp, u64* __restrict__ hx,
        unsigned short* __restrict__ hsP, int* __restrict__ prog,
        const unsigned short* __restrict__ WvP, const float* __restrict__ bvoc,
        const int* __restrict__ captions, float* __restrict__ pmax,
        float* __restrict__ psum, float* __restrict__ tlog){
    __shared__ unsigned int hstage[4096];   // 16 KB (lstm role)
    __shared__ float a_s[4][16][16];        // 4 KB  (lstm role)
    __shared__ int   tgt_s[64];             // vocab role
    __shared__ float wmax_s[4][64], wsum_s[4][64];
    int tid = threadIdx.x;       // 0..255

    if (blockIdx.x >= NWG){
        // ================= vocab role =================
        int vid = blockIdx.x - NWG;         // 0..7999
        int pri = vid / 2000;               // readiness group
        int idx = vid % 2000;
        int bm  = (idx % 16) * 4 + pri;     // bm fastest: 16 siblings share bn
        int bn  = idx / 16;                 // 0..124
        int need = (pri + 1) * 4;           // lstm chunks (16 steps each) required

        if (tid == 0){
            int cnt = 0;
            for (;;){
                int mn = 1 << 30;
                for (int i = 0; i < 32; ++i){
                    int p = AGLOAD(&prog[i]);
                    mn = p < mn ? p : mn;
                }
                if (mn >= need) break;
                __builtin_amdgcn_s_sleep(32);
                if (++cnt > SPINCAP) break;   // escape hatch (never in practice)
            }
        }
        __syncthreads();

        int wv = tid >> 6, L = tid & 63;
        int q = L >> 4, ln = L & 15;
        if (tid < 64){
            int rg = bm*64 + tid;
            tgt_s[tid] = captions[(rg >> 8)*257 + (rg & 255) + 1];
        }
        __syncthreads();
        f32x4 acc[4][4];
        for (int mt=0;mt<4;++mt) for (int nt=0;nt<4;++nt) acc[mt][nt] = (f32x4){0.f,0.f,0.f,0.f};
        int colb = bn*256 + wv*64;
        const unsigned short* aB = hsP + ((long)(bm*4)*16)*512;        // rb = bm*4 + mt
        const unsigned short* bB = WvP + ((long)(bn*16 + wv*4)*16)*512; // vb = bn*16+wv*4+nt
        #pragma unroll 4
        for (int kt = 0; kt < 16; ++kt){
            short8 a[4], bb[4];
            #pragma unroll
            for (int mt=0;mt<4;++mt)
                a[mt] = *(const short8*)(aB + ((long)(mt*16 + kt)*64 + L)*8);
            #pragma unroll
            for (int nt=0;nt<4;++nt)
                bb[nt] = *(const short8*)(bB + ((long)(nt*16 + kt)*64 + L)*8);
            #pragma unroll
            for (int mt=0;mt<4;++mt)
                #pragma unroll
                for (int nt=0;nt<4;++nt)
                    acc[mt][nt] = __builtin_amdgcn_mfma_f32_16x16x32_bf16(a[mt], bb[nt], acc[mt][nt], 0,0,0);
        }
        float bv[4];
        #pragma unroll
        for (int nt=0;nt<4;++nt) bv[nt] = bvoc[colb + nt*16 + ln];
        #pragma unroll
        for (int mt=0;mt<4;++mt) for (int nt=0;nt<4;++nt) for (int r=0;r<4;++r)
            acc[mt][nt][r] += bv[nt];
        // target-logit grab (exactly one lane grid-wide matches per row)
        #pragma unroll
        for (int mt=0;mt<4;++mt) for (int r=0;r<4;++r){
            int rl = mt*16 + q*4 + r;
            int tg = tgt_s[rl] - colb;
            if (tg >= 0 && tg < 64){
                int nt = tg >> 4;
                if ((tg & 15) == ln) tlog[bm*64 + rl] = acc[mt][nt][r];
            }
        }
        // per-row max & sumexp over this block's 256 cols
        #pragma unroll
        for (int mt=0;mt<4;++mt){
            #pragma unroll
            for (int r=0;r<4;++r){
                float m = fmaxf(fmaxf(acc[mt][0][r],acc[mt][1][r]), fmaxf(acc[mt][2][r],acc[mt][3][r]));
                for (int d=1; d<16; d<<=1) m = fmaxf(m, __shfl_xor(m, d, 16));
                float s = __expf(acc[mt][0][r]-m) + __expf(acc[mt][1][r]-m)
                        + __expf(acc[mt][2][r]-m) + __expf(acc[mt][3][r]-m);
                for (int d=1; d<16; d<<=1) s += __shfl_xor(s, d, 16);
                if (ln == 0){ int rl = mt*16 + q*4 + r; wmax_s[wv][rl] = m; wsum_s[wv][rl] = s; }
            }
        }
        __syncthreads();
        if (tid < 64){
            float M = fmaxf(fmaxf(wmax_s[0][tid],wmax_s[1][tid]), fmaxf(wmax_s[2][tid],wmax_s[3][tid]));
            float S = 0.f;
            for (int ww=0; ww<4; ++ww) S += wsum_s[ww][tid]*__expf(wmax_s[ww][tid]-M);
            pmax[(long)bn*NROWS + bm*64 + tid] = M;
            psum[(long)bn*NROWS + bm*64 + tid] = S;
        }
        return;
    }

    // ================= lstm role (verified round-1 protocol) =================
    int w = blockIdx.x;          // 0..31
    int wv = tid >> 6;           // wave = gate = N-tile (0..3)
    int L = tid & 63;
    int q = L >> 4, ln = L & 15;
    int s_idx = tid >> 4, jl = tid & 15;   // (sequence, local hidden unit)

    // Wh B-fragments -> registers (wave wv uses fragments kt*4+wv only)
    short8 bw[16];
    #pragma unroll
    for (int kt = 0; kt < 16; ++kt)
        bw[kt] = *(const short8*)(Whp + ((long)w*4096 + (kt*4+wv)*64 + L)*8);

    float c_r = 0.f;
    int fq_pub = (w>>1)*4 + (w&1)*2 + (jl>>3);
    int pubIdx = fq_pub*64 + s_idx*4 + ((jl>>1)&3);
    int kt_h = w >> 1;
    int q_h  = ((w & 1) << 1) | (jl >> 3);
    int j_h  = jl & 7;
    unsigned int* hsP32 = (unsigned int*)hsP;

    for (int t = 0; t < TSTEPS; ++t){
        // xw loads first: HBM latency overlaps the poll
        long xb = (long)(t*16 + s_idx)*GATES + w*16 + jl;
        float xg0 = xw[xb], xg1 = xw[xb+512], xg2 = xw[xb+1024], xg3 = xw[xb+1536];

        const u64* hr = hx + (t & 1)*4096;
        u64*       hw = hx + ((t+1) & 1)*4096;

        // ---- poll + stage: 16 coalesced u64/thread, spin until all tags == t
        u64 v[16];
        #pragma unroll
        for (int i = 0; i < 16; ++i)
            v[i] = AGLOAD(hr + tid + i*256);
        for (;;){
            u64 bad = 0;
            #pragma unroll
            for (int i = 0; i < 16; ++i) bad |= (v[i] >> 32) ^ (u64)(unsigned)t;
            if (!bad) break;
            #pragma unroll
            for (int i = 0; i < 16; ++i)
                v[i] = AGLOAD(hr + tid + i*256);
        }
        #pragma unroll
        for (int i = 0; i < 16; ++i) hstage[tid + i*256] = (unsigned)v[i];
        __syncthreads();   // S1: stage complete (also orders vs prev a_s reads)

        // ---- MFMA: A-frag (kt,q,ln) = 4 contiguous u32 (linear sweep)
        f32x4 acc = {0.f,0.f,0.f,0.f};
        #pragma unroll
        for (int kt = 0; kt < 16; ++kt){
            short8 a = *(const short8*)((const unsigned short*)hstage + (kt*256 + q*64 + ln*4)*2);
            acc = __builtin_amdgcn_mfma_f32_16x16x32_bf16(a, bw[kt], acc, 0, 0, 0);
        }
        #pragma unroll
        for (int r = 0; r < 4; ++r) a_s[wv][q*4 + r][ln] = acc[r];
        __syncthreads();   // S2: a_s complete (also: all hstage reads done)

        // ---- gate phase
        float ai = a_s[0][s_idx][jl] + xg0;
        float af = a_s[1][s_idx][jl] + xg1;
        float ao = a_s[2][s_idx][jl] + xg2;
        float ag = a_s[3][s_idx][jl] + xg3;
        float ig = 1.f/(1.f + __expf(-ai));
        float fg = 1.f/(1.f + __expf(-af));
        float og = 1.f/(1.f + __expf(-ao));
        float gg = 2.f/(1.f + __expf(-2.f*ag)) - 1.f;
        c_r = fg*c_r + ig*gg;
        float hv = og * (2.f/(1.f + __expf(-2.f*c_r)) - 1.f);
        unsigned short hb = f2bf(hv);

        // ---- publish h (tagged u64) + hsP (agent u32 pair), fire-and-forget
        int hv32 = (int)hb;
        int other = __shfl(hv32, L ^ 1);
        int rb = s_idx*16 + (t >> 4);
        if ((jl & 1) == 0){
            u64 pk = (u64)(unsigned short)hv32
                   | ((u64)(unsigned short)other << 16)
                   | ((u64)(unsigned)(t+1) << 32);
            __hip_atomic_store(hw + pubIdx, pk, __ATOMIC_RELAXED, __HIP_MEMORY_SCOPE_AGENT);
            unsigned int hp = (unsigned int)(unsigned short)hv32
                            | ((unsigned int)(unsigned short)other << 16);
            // u32 index = u16 index / 2 (j_h is even here)
            __hip_atomic_store(hsP32 + (((long)(rb*16 + kt_h))*64 + q_h*16 + (t & 15))*4 + (j_h >> 1),
                               hp, __ATOMIC_RELAXED, __HIP_MEMORY_SCOPE_AGENT);
        }
        // ---- chunk boundary: drain stores, then publish progress
        if ((t & 15) == 15){
            asm volatile("s_waitcnt vmcnt(0)" ::: "memory");
            __syncthreads();
            if (tid == 0)
                __hip_atomic_store(&prog[w], (t >> 4) + 1, __ATOMIC_RELAXED, __HIP_MEMORY_SCOPE_AGENT);
        }
    }
}

// ---------------------------------------------------------------- K4:
// combine 125 partials per row -> lse -> masked NLL -> loss/N
__global__ __launch_bounds__(256) void reduce_loss(const float* __restrict__ pmax,
        const float* __restrict__ psum, const float* __restrict__ tlog,
        const int* __restrict__ captions, float* __restrict__ out){
    int r = blockIdx.x*256 + threadIdx.x;
    float M = -1e30f;
    for (int p=0;p<NVB;++p) M = fmaxf(M, pmax[(long)p*NROWS + r]);
    float S = 0.f;
    for (int p=0;p<NVB;++p) S += psum[(long)p*NROWS + r]*__expf(pmax[(long)p*NROWS + r]-M);
    float lse = M + logf(S);
    float nll = lse - tlog[r];
    int tok = captions[(r >> 8)*257 + (r & 255) + 1];
    float val = (tok != 0) ? nll : 0.f;
    __shared__ float red[256];
    red[threadIdx.x] = val; __syncthreads();
    for (int s=128; s>0; s>>=1){
        if (threadIdx.x < s) red[threadIdx.x] += red[threadIdx.x+s];
        __syncthreads();
    }
    if (threadIdx.x == 0) atomicAdd(out, red[0] * (1.0f/16.0f));
}

// ---------------------------------------------------------------- launch
extern "C" void kernel_launch(void* const* d_in, const int* in_sizes, int n_in,
                              void* d_out, int out_size, void* d_ws, size_t ws_size,
                              hipStream_t stream){
    const int*   captions = (const int*)  d_in[0];
    const float* Wemb     = (const float*)d_in[1];
    const float* Wx       = (const float*)d_in[2];
    const float* Wh       = (const float*)d_in[3];
    const float* b        = (const float*)d_in[4];
    const float* Wv       = (const float*)d_in[5];
    const float* bvoc     = (const float*)d_in[6];
    const float* h_init   = (const float*)d_in[7];

    char* ws = (char*)d_ws;
    float*          xw   = (float*)         (ws + 0);          // 33554432 B
    unsigned short* WvP  = (unsigned short*)(ws + 33554432);   // 32768000 B
    unsigned short* hsP  = (unsigned short*)(ws + 66322432);   //  4194304 B
    float*          pmax = (float*)         (ws + 70516736);   //  2048000 B
    float*          psum = (float*)         (ws + 72564736);   //  2048000 B
    float*          tlog = (float*)         (ws + 74612736);   //    16384 B
    unsigned short* Whp  = (unsigned short*)(ws + 74629120);   //  2097152 B
    u64*            hx   = (u64*)           (ws + 76726272);   //    65536 B (2 bufs x 4096 u64)
    int*            prog = (int*)           (ws + 76791808);   //      128 B (32 progress ctrs)

    float* out_f = (float*)d_out;

    (void)hipMemsetAsync(d_out, 0, sizeof(float), stream);

    hipLaunchKernelGGL(prep_all,    dim3(4560),       dim3(256), 0, stream,
                       captions, Wemb, Wx, b, xw, Wh, Whp, h_init, hx, Wv, WvP, prog);
    hipLaunchKernelGGL(lstm_vocab,  dim3(NWG+NVBLK),  dim3(256), 0, stream,
                       xw, Whp, hx, hsP, prog, WvP, bvoc, captions, pmax, psum, tlog);
    hipLaunchKernelGGL(reduce_loss, dim3(16),         dim3(256), 0, stream,
                       pmax, psum, tlog, captions, out_f);
}

// Round 8
// 1046.770 us; speedup vs baseline: 13.7203x; 1.0126x over previous
//
#include <hip/hip_runtime.h>

#define VOCAB   32000
#define WORDVEC 256
#define HIDDEN  512
#define TSTEPS  256
#define NBATCH  16
#define NROWS   (TSTEPS*NBATCH)   // 4096
#define GATES   (4*HIDDEN)        // 2048
#define NVB     125               // 32000/256
#define NWG     32                // LSTM worker WGs (32 x 16 hidden units)
#define NVBLK   8000              // vocab blocks (64 bm x 125 bn)
#define SPINCAP (1<<16)           // bounded readiness spin (escape hatch)

typedef __attribute__((ext_vector_type(8))) short short8;
typedef __attribute__((ext_vector_type(4))) float f32x4;
typedef unsigned long long u64;

#define AGLOAD(p) __hip_atomic_load((p), __ATOMIC_RELAXED, __HIP_MEMORY_SCOPE_AGENT)
#define MFMA16(a,b,c) __builtin_amdgcn_mfma_f32_16x16x32_bf16((a),(b),(c),0,0,0)

__device__ __forceinline__ unsigned short f2bf(float x){
    union { float f; unsigned int u; } v; v.f = x;
    unsigned int r = v.u + 0x7fffu + ((v.u >> 16) & 1u);
    return (unsigned short)(r >> 16);
}

// ---------------------------------------------------------------- K_prep:
// One launch, four independent jobs selected by blockIdx.x:
//   [0,512)     embed_xw : xw[r][k] = b[k] + W_embed[tok]@Wx
//   [512,544)   whp_prep : Wh -> per-WG MFMA-B-fragment bf16 image
//   [544,560)   hg_init  : h_0 -> tagged-pair exchange buffer 0 (+prog=0)
//   [560,4560)  wv_pack  : W_vocab -> MFMA-B-fragment-linear bf16
__global__ __launch_bounds__(256) void prep_all(const int* __restrict__ captions,
        const float* __restrict__ Wemb, const float* __restrict__ Wx,
        const float* __restrict__ b, float* __restrict__ xw,
        const float* __restrict__ Wh, unsigned short* __restrict__ Whp,
        const float* __restrict__ h_init, u64* __restrict__ hx,
        const float* __restrict__ Wv, unsigned short* __restrict__ WvP,
        int* __restrict__ prog){
    __shared__ float s[64][65];    // wv role (16.6 KB) -- also covers xs (8 KB)
    float (*xs)[WORDVEC] = (float(*)[WORDVEC])s;
    __shared__ int toks[8];
    int bid = blockIdx.x;
    int tid = threadIdx.x;
    if (bid < 512){
        // ---------------- embed_xw ----------------
        int r0 = bid * 8;
        if (tid < 8){
            int r = r0 + tid; int t = r >> 4, n = r & 15;
            toks[tid] = captions[n*257 + t];
        }
        __syncthreads();
        for (int i = 0; i < 8; ++i){
            int lin = tid + i*256;
            int ri = lin >> 8, d = lin & 255;
            xs[ri][d] = Wemb[(long)toks[ri]*WORDVEC + d];
        }
        __syncthreads();
        float4 b0 = *(const float4*)(b + tid*4);
        float4 b1 = *(const float4*)(b + 1024 + tid*4);
        float acc[8][8];
        for (int ri = 0; ri < 8; ++ri){
            acc[ri][0]=b0.x; acc[ri][1]=b0.y; acc[ri][2]=b0.z; acc[ri][3]=b0.w;
            acc[ri][4]=b1.x; acc[ri][5]=b1.y; acc[ri][6]=b1.z; acc[ri][7]=b1.w;
        }
        for (int d = 0; d < WORDVEC; ++d){
            float4 w0 = *(const float4*)(Wx + (long)d*GATES + tid*4);
            float4 w1 = *(const float4*)(Wx + (long)d*GATES + 1024 + tid*4);
            #pragma unroll
            for (int ri = 0; ri < 8; ++ri){
                float xv = xs[ri][d];
                acc[ri][0] += xv*w0.x; acc[ri][1] += xv*w0.y;
                acc[ri][2] += xv*w0.z; acc[ri][3] += xv*w0.w;
                acc[ri][4] += xv*w1.x; acc[ri][5] += xv*w1.y;
                acc[ri][6] += xv*w1.z; acc[ri][7] += xv*w1.w;
            }
        }
        for (int ri = 0; ri < 8; ++ri){
            float4 o0 = {acc[ri][0],acc[ri][1],acc[ri][2],acc[ri][3]};
            float4 o1 = {acc[ri][4],acc[ri][5],acc[ri][6],acc[ri][7]};
            *(float4*)(xw + (long)(r0+ri)*GATES + tid*4) = o0;
            *(float4*)(xw + (long)(r0+ri)*GATES + 1024 + tid*4) = o1;
        }
    } else if (bid < 544){
        // ---------------- whp_prep ----------------
        int w = bid - 512;
        for (int item = tid; item < 4096; item += 256){
            int f = item >> 6;          // 0..63
            int L = item & 63;
            int kt = f >> 2, nt = f & 3;
            int q = L >> 4, ln = L & 15;
            int col = nt*HIDDEN + w*16 + ln;   // gate nt, unit w*16+ln
            short8 vvec;
            for (int jj = 0; jj < 8; ++jj){
                int k = kt*32 + q*8 + jj;
                vvec[jj] = (short)f2bf(Wh[(long)k*GATES + col]);
            }
            *(short8*)(Whp + ((long)w*4096 + item)*8) = vvec;
        }
    } else if (bid < 560){
        // ---------------- hg_init (+ progress zero) ----------------
        if (bid == 544 && tid < 32) prog[tid] = 0;
        int p = (bid - 544)*256 + tid;   // 4096 pairs
        int fq = p >> 6;
        int j  = (p & 3) * 2;
        int u0 = (fq>>2)*32 + (fq&3)*8 + j;
        u64 pk = (u64)f2bf(h_init[u0]) | ((u64)f2bf(h_init[u0+1]) << 16);   // tag 0
        hx[p] = pk;
    } else {
        // ---------------- wv_pack ----------------
        int tile = bid - 560;               // 0..3999
        int v0 = (tile >> 3) * 64;          // 500 column-tiles
        int k0 = (tile & 7) * 64;           // 8 row-tiles
        for (int i = 0; i < 16; ++i){
            int lin = tid + i*256;
            int kk = lin >> 6, vv = lin & 63;
            s[kk][vv] = Wv[(long)(k0+kk)*VOCAB + v0 + vv];
        }
        __syncthreads();
        for (int i = 0; i < 2; ++i){
            int lr = tid + i*256;          // 0..511 lane-rows
            int f  = lr >> 6;              // 0..7: vbl(0..3) x ktl(0..1)
            int vbl = f >> 1, ktl = f & 1;
            int L = lr & 63, q = L >> 4, ln = L & 15;
            short8 o;
            #pragma unroll
            for (int j = 0; j < 8; ++j)
                o[j] = (short)f2bf(s[ktl*32 + q*8 + j][vbl*16 + ln]);
            long vb = (long)(tile >> 3)*4 + vbl;
            long kt = (long)(tile & 7)*2 + ktl;
            *(short8*)(WvP + ((vb*16 + kt)*64 + L)*8) = o;
        }
    }
}

// ---------------------------------------------------------------- K2:
// Fused LSTM + vocab GEMM.
//   blocks [0,32):      verified LSTM recurrence (tagged-u64 agent exchange);
//                       hsP published via agent-scope u32 pair-stores;
//                       every 16 steps: vmcnt drain + barrier + prog[w]=chunk.
//   blocks [32,8032):   vocab GEMM (BM=64, BN=256) ordered by readiness group;
//                       XCD-banded within a group (blocks sharing a WvP slice
//                       land on one XCD's L2, assuming round-robin dispatch).
// Round-8 spill fix: vocab kt-loop split into 2x2 MFMA sub-groups with
// sched_barrier(0) separators -> peak liveness ~88 VGPR, BELOW the
// allocator's chosen 92 budget (rounds 6/7 spilled ~790 MB of scratch).
__global__ __launch_bounds__(256) void lstm_vocab(const float* __restrict__ xw,
        const unsigned short* __restrict__ Whp, u64* __restrict__ hx,
        unsigned short* __restrict__ hsP, int* __restrict__ prog,
        const unsigned short* __restrict__ WvP, const float* __restrict__ bvoc,
        const int* __restrict__ captions, float* __restrict__ pmax,
        float* __restrict__ psum, float* __restrict__ tlog){
    __shared__ unsigned int hstage[4096];   // 16 KB (lstm role)
    __shared__ float a_s[4][16][16];        // 4 KB  (lstm role)
    __shared__ int   tgt_s[64];             // vocab role
    __shared__ float wmax_s[4][64], wsum_s[4][64];
    int tid = threadIdx.x;       // 0..255

    if (blockIdx.x >= NWG){
        // ================= vocab role =================
        int vid = blockIdx.x - NWG;         // 0..7999
        int pri = vid / 2000;               // readiness group
        int idx = vid % 2000;
        // XCD banding: blocks with the same (blockIdx % 8) XCD get contiguous
        // (bn, all-16-bm) runs -> per-XCD L2 holds one 256KB WvP slice at a time.
        int p   = (idx & 7)*250 + (idx >> 3);   // bijective within [0,2000)
        int bn  = p >> 4;                   // 0..124
        int bm  = (p & 15)*4 + pri;         // bm in group pri
        int need = (pri + 1) * 4;           // lstm chunks (16 steps each) required

        if (tid == 0){
            int cnt = 0;
            for (;;){
                int mn = 1 << 30;
                for (int i = 0; i < 32; ++i){
                    int pv = AGLOAD(&prog[i]);
                    mn = pv < mn ? pv : mn;
                }
                if (mn >= need) break;
                __builtin_amdgcn_s_sleep(32);
                if (++cnt > SPINCAP) break;   // escape hatch (never in practice)
            }
        }
        __syncthreads();

        int wv = tid >> 6, L = tid & 63;
        int q = L >> 4, ln = L & 15;
        if (tid < 64){
            int rg = bm*64 + tid;
            tgt_s[tid] = captions[(rg >> 8)*257 + (rg & 255) + 1];
        }
        __syncthreads();
        f32x4 acc[4][4];
        for (int mt=0;mt<4;++mt) for (int nt=0;nt<4;++nt) acc[mt][nt] = (f32x4){0.f,0.f,0.f,0.f};
        int colb = bn*256 + wv*64;
        // u16 bases incl. lane offset; frag stride 512 u16 (1KB), mt/nt stride 8192 u16
        const unsigned short* aB = hsP + ((long)(bm*4)*16)*512 + (long)L*8;
        const unsigned short* bB = WvP + ((long)(bn*16 + wv*4)*16)*512 + (long)L*8;
        #pragma unroll 1
        for (int kt = 0; kt < 16; ++kt){
            const short8* aK = (const short8*)(aB + (long)kt*512);   // short8 idx: *16B
            const short8* bK = (const short8*)(bB + (long)kt*512);
            // G(m01,n01)
            short8 a0 = aK[0],    a1 = aK[1024];
            short8 b0 = bK[0],    b1 = bK[1024];
            acc[0][0] = MFMA16(a0,b0,acc[0][0]); acc[0][1] = MFMA16(a0,b1,acc[0][1]);
            acc[1][0] = MFMA16(a1,b0,acc[1][0]); acc[1][1] = MFMA16(a1,b1,acc[1][1]);
            __builtin_amdgcn_sched_barrier(0);
            // G(m01,n23): reuse a0,a1
            short8 b2 = bK[2048], b3 = bK[3072];
            acc[0][2] = MFMA16(a0,b2,acc[0][2]); acc[0][3] = MFMA16(a0,b3,acc[0][3]);
            acc[1][2] = MFMA16(a1,b2,acc[1][2]); acc[1][3] = MFMA16(a1,b3,acc[1][3]);
            __builtin_amdgcn_sched_barrier(0);
            // G(m23,n23): reuse b2,b3
            short8 a2 = aK[2048], a3 = aK[3072];
            acc[2][2] = MFMA16(a2,b2,acc[2][2]); acc[2][3] = MFMA16(a2,b3,acc[2][3]);
            acc[3][2] = MFMA16(a3,b2,acc[3][2]); acc[3][3] = MFMA16(a3,b3,acc[3][3]);
            __builtin_amdgcn_sched_barrier(0);
            // G(m23,n01): reuse a2,a3; RELOAD b0,b1 via opaque addr (defeats GVN
            // so the first b0,b1 don't stay live across the middle groups)
            u64 bKo = (u64)bK; asm volatile("" : "+v"(bKo));
            const short8* bK2 = (const short8*)bKo;
            short8 c0 = bK2[0], c1 = bK2[1024];
            acc[2][0] = MFMA16(a2,c0,acc[2][0]); acc[2][1] = MFMA16(a2,c1,acc[2][1]);
            acc[3][0] = MFMA16(a3,c0,acc[3][0]); acc[3][1] = MFMA16(a3,c1,acc[3][1]);
            __builtin_amdgcn_sched_barrier(0);
        }
        float bv[4];
        #pragma unroll
        for (int nt=0;nt<4;++nt) bv[nt] = bvoc[colb + nt*16 + ln];
        #pragma unroll
        for (int mt=0;mt<4;++mt) for (int nt=0;nt<4;++nt) for (int r=0;r<4;++r)
            acc[mt][nt][r] += bv[nt];
        // target-logit grab (exactly one lane grid-wide matches per row)
        #pragma unroll
        for (int mt=0;mt<4;++mt) for (int r=0;r<4;++r){
            int rl = mt*16 + q*4 + r;
            int tg = tgt_s[rl] - colb;
            if (tg >= 0 && tg < 64){
                int nt = tg >> 4;
                if ((tg & 15) == ln) tlog[bm*64 + rl] = acc[mt][nt][r];
            }
        }
        // per-row max & sumexp over this block's 256 cols
        #pragma unroll
        for (int mt=0;mt<4;++mt){
            #pragma unroll
            for (int r=0;r<4;++r){
                float m = fmaxf(fmaxf(acc[mt][0][r],acc[mt][1][r]), fmaxf(acc[mt][2][r],acc[mt][3][r]));
                for (int d=1; d<16; d<<=1) m = fmaxf(m, __shfl_xor(m, d, 16));
                float s = __expf(acc[mt][0][r]-m) + __expf(acc[mt][1][r]-m)
                        + __expf(acc[mt][2][r]-m) + __expf(acc[mt][3][r]-m);
                for (int d=1; d<16; d<<=1) s += __shfl_xor(s, d, 16);
                if (ln == 0){ int rl = mt*16 + q*4 + r; wmax_s[wv][rl] = m; wsum_s[wv][rl] = s; }
            }
        }
        __syncthreads();
        if (tid < 64){
            float M = fmaxf(fmaxf(wmax_s[0][tid],wmax_s[1][tid]), fmaxf(wmax_s[2][tid],wmax_s[3][tid]));
            float S = 0.f;
            for (int ww=0; ww<4; ++ww) S += wsum_s[ww][tid]*__expf(wmax_s[ww][tid]-M);
            pmax[(long)bn*NROWS + bm*64 + tid] = M;
            psum[(long)bn*NROWS + bm*64 + tid] = S;
        }
        return;
    }

    // ================= lstm role (verified round-1 protocol) =================
    int w = blockIdx.x;          // 0..31
    int wv = tid >> 6;           // wave = gate = N-tile (0..3)
    int L = tid & 63;
    int q = L >> 4, ln = L & 15;
    int s_idx = tid >> 4, jl = tid & 15;   // (sequence, local hidden unit)

    // Wh B-fragments -> registers (wave wv uses fragments kt*4+wv only)
    short8 bw[16];
    #pragma unroll
    for (int kt = 0; kt < 16; ++kt)
        bw[kt] = *(const short8*)(Whp + ((long)w*4096 + (kt*4+wv)*64 + L)*8);

    float c_r = 0.f;
    int fq_pub = (w>>1)*4 + (w&1)*2 + (jl>>3);
    int pubIdx = fq_pub*64 + s_idx*4 + ((jl>>1)&3);
    int kt_h = w >> 1;
    int q_h  = ((w & 1) << 1) | (jl >> 3);
    int j_h  = jl & 7;
    unsigned int* hsP32 = (unsigned int*)hsP;

    for (int t = 0; t < TSTEPS; ++t){
        // xw loads first: HBM latency overlaps the poll
        long xb = (long)(t*16 + s_idx)*GATES + w*16 + jl;
        float xg0 = xw[xb], xg1 = xw[xb+512], xg2 = xw[xb+1024], xg3 = xw[xb+1536];

        const u64* hr = hx + (t & 1)*4096;
        u64*       hw = hx + ((t+1) & 1)*4096;

        // ---- poll + stage: 16 coalesced u64/thread, spin until all tags == t
        u64 v[16];
        #pragma unroll
        for (int i = 0; i < 16; ++i)
            v[i] = AGLOAD(hr + tid + i*256);
        for (;;){
            u64 bad = 0;
            #pragma unroll
            for (int i = 0; i < 16; ++i) bad |= (v[i] >> 32) ^ (u64)(unsigned)t;
            if (!bad) break;
            #pragma unroll
            for (int i = 0; i < 16; ++i)
                v[i] = AGLOAD(hr + tid + i*256);
        }
        #pragma unroll
        for (int i = 0; i < 16; ++i) hstage[tid + i*256] = (unsigned)v[i];
        __syncthreads();   // S1: stage complete (also orders vs prev a_s reads)

        // ---- MFMA: A-frag (kt,q,ln) = 4 contiguous u32 (linear sweep)
        f32x4 acc = {0.f,0.f,0.f,0.f};
        #pragma unroll
        for (int kt = 0; kt < 16; ++kt){
            short8 a = *(const short8*)((const unsigned short*)hstage + (kt*256 + q*64 + ln*4)*2);
            acc = MFMA16(a, bw[kt], acc);
        }
        #pragma unroll
        for (int r = 0; r < 4; ++r) a_s[wv][q*4 + r][ln] = acc[r];
        __syncthreads();   // S2: a_s complete (also: all hstage reads done)

        // ---- gate phase
        float ai = a_s[0][s_idx][jl] + xg0;
        float af = a_s[1][s_idx][jl] + xg1;
        float ao = a_s[2][s_idx][jl] + xg2;
        float ag = a_s[3][s_idx][jl] + xg3;
        float ig = 1.f/(1.f + __expf(-ai));
        float fg = 1.f/(1.f + __expf(-af));
        float og = 1.f/(1.f + __expf(-ao));
        float gg = 2.f/(1.f + __expf(-2.f*ag)) - 1.f;
        c_r = fg*c_r + ig*gg;
        float hv = og * (2.f/(1.f + __expf(-2.f*c_r)) - 1.f);
        unsigned short hb = f2bf(hv);

        // ---- publish h (tagged u64) + hsP (agent u32 pair), fire-and-forget
        int hv32 = (int)hb;
        int other = __shfl(hv32, L ^ 1);
        int rb = s_idx*16 + (t >> 4);
        if ((jl & 1) == 0){
            u64 pk = (u64)(unsigned short)hv32
                   | ((u64)(unsigned short)other << 16)
                   | ((u64)(unsigned)(t+1) << 32);
            __hip_atomic_store(hw + pubIdx, pk, __ATOMIC_RELAXED, __HIP_MEMORY_SCOPE_AGENT);
            unsigned int hp = (unsigned int)(unsigned short)hv32
                            | ((unsigned int)(unsigned short)other << 16);
            // u32 index = u16 index / 2 (j_h is even here)
            __hip_atomic_store(hsP32 + (((long)(rb*16 + kt_h))*64 + q_h*16 + (t & 15))*4 + (j_h >> 1),
                               hp, __ATOMIC_RELAXED, __HIP_MEMORY_SCOPE_AGENT);
        }
        // ---- chunk boundary: drain stores, then publish progress
        if ((t & 15) == 15){
            asm volatile("s_waitcnt vmcnt(0)" ::: "memory");
            __syncthreads();
            if (tid == 0)
                __hip_atomic_store(&prog[w], (t >> 4) + 1, __ATOMIC_RELAXED, __HIP_MEMORY_SCOPE_AGENT);
        }
    }
}

// ---------------------------------------------------------------- K4:
// combine 125 partials per row -> lse -> masked NLL -> loss/N
__global__ __launch_bounds__(256) void reduce_loss(const float* __restrict__ pmax,
        const float* __restrict__ psum, const float* __restrict__ tlog,
        const int* __restrict__ captions, float* __restrict__ out){
    int r = blockIdx.x*256 + threadIdx.x;
    float M = -1e30f;
    for (int p=0;p<NVB;++p) M = fmaxf(M, pmax[(long)p*NROWS + r]);
    float S = 0.f;
    for (int p=0;p<NVB;++p) S += psum[(long)p*NROWS + r]*__expf(pmax[(long)p*NROWS + r]-M);
    float lse = M + logf(S);
    float nll = lse - tlog[r];
    int tok = captions[(r >> 8)*257 + (r & 255) + 1];
    float val = (tok != 0) ? nll : 0.f;
    __shared__ float red[256];
    red[threadIdx.x] = val; __syncthreads();
    for (int s=128; s>0; s>>=1){
        if (threadIdx.x < s) red[threadIdx.x] += red[threadIdx.x+s];
        __syncthreads();
    }
    if (threadIdx.x == 0) atomicAdd(out, red[0] * (1.0f/16.0f));
}

// ---------------------------------------------------------------- launch
extern "C" void kernel_launch(void* const* d_in, const int* in_sizes, int n_in,
                              void* d_out, int out_size, void* d_ws, size_t ws_size,
                              hipStream_t stream){
    const int*   captions = (const int*)  d_in[0];
    const float* Wemb     = (const float*)d_in[1];
    const float* Wx       = (const float*)d_in[2];
    const float* Wh       = (const float*)d_in[3];
    const float* b        = (const float*)d_in[4];
    const float* Wv       = (const float*)d_in[5];
    const float* bvoc     = (const float*)d_in[6];
    const float* h_init   = (const float*)d_in[7];

    char* ws = (char*)d_ws;
    float*          xw   = (float*)         (ws + 0);          // 33554432 B
    unsigned short* WvP  = (unsigned short*)(ws + 33554432);   // 32768000 B
    unsigned short* hsP  = (unsigned short*)(ws + 66322432);   //  4194304 B
    float*          pmax = (float*)         (ws + 70516736);   //  2048000 B
    float*          psum = (float*)         (ws + 72564736);   //  2048000 B
    float*          tlog = (float*)         (ws + 74612736);   //    16384 B
    unsigned short* Whp  = (unsigned short*)(ws + 74629120);   //  2097152 B
    u64*            hx   = (u64*)           (ws + 76726272);   //    65536 B (2 bufs x 4096 u64)
    int*            prog = (int*)           (ws + 76791808);   //      128 B (32 progress ctrs)

    float* out_f = (float*)d_out;

    (void)hipMemsetAsync(d_out, 0, sizeof(float), stream);

    hipLaunchKernelGGL(prep_all,    dim3(4560),       dim3(256), 0, stream,
                       captions, Wemb, Wx, b, xw, Wh, Whp, h_init, hx, Wv, WvP, prog);
    hipLaunchKernelGGL(lstm_vocab,  dim3(NWG+NVBLK),  dim3(256), 0, stream,
                       xw, Whp, hx, hsP, prog, WvP, bvoc, captions, pmax, psum, tlog);
    hipLaunchKernelGGL(reduce_loss, dim3(16),         dim3(256), 0, stream,
                       pmax, psum, tlog, captions, out_f);
}

// Round 9
// 1006.116 us; speedup vs baseline: 14.2747x; 1.0404x over previous
//
#include <hip/hip_runtime.h>

#define VOCAB   32000
#define WORDVEC 256
#define HIDDEN  512
#define TSTEPS  256
#define NBATCH  16
#define NROWS   (TSTEPS*NBATCH)   // 4096
#define GATES   (4*HIDDEN)        // 2048
#define NVB     125               // 32000/256
#define NWG     32                // LSTM worker WGs (32 x 16 hidden units)
#define NVBLK   8000              // vocab blocks (64 bm x 125 bn)
#define SPINCAP (1<<16)           // bounded readiness spin (escape hatch)

typedef __attribute__((ext_vector_type(8))) short short8;
typedef __attribute__((ext_vector_type(4))) float f32x4;
typedef unsigned long long u64;

#define AGLOAD(p) __hip_atomic_load((p), __ATOMIC_RELAXED, __HIP_MEMORY_SCOPE_AGENT)
#define MFMA16(a,b,c) __builtin_amdgcn_mfma_f32_16x16x32_bf16((a),(b),(c),0,0,0)

__device__ __forceinline__ unsigned short f2bf(float x){
    union { float f; unsigned int u; } v; v.f = x;
    unsigned int r = v.u + 0x7fffu + ((v.u >> 16) & 1u);
    return (unsigned short)(r >> 16);
}

// ---------------------------------------------------------------- K_prep:
// One launch, four independent jobs selected by blockIdx.x:
//   [0,512)     embed_xw : xw[r][k] = b[k] + W_embed[tok]@Wx
//   [512,544)   whp_prep : Wh -> per-WG MFMA-B-fragment bf16 image
//   [544,560)   hg_init  : h_0 -> tagged-pair exchange buffer 0 (+prog=0)
//   [560,4560)  wv_pack  : W_vocab -> MFMA-B-fragment-linear bf16
__global__ __launch_bounds__(256) void prep_all(const int* __restrict__ captions,
        const float* __restrict__ Wemb, const float* __restrict__ Wx,
        const float* __restrict__ b, float* __restrict__ xw,
        const float* __restrict__ Wh, unsigned short* __restrict__ Whp,
        const float* __restrict__ h_init, u64* __restrict__ hx,
        const float* __restrict__ Wv, unsigned short* __restrict__ WvP,
        int* __restrict__ prog){
    __shared__ float s[64][65];    // wv role (16.6 KB) -- also covers xs (8 KB)
    float (*xs)[WORDVEC] = (float(*)[WORDVEC])s;
    __shared__ int toks[8];
    int bid = blockIdx.x;
    int tid = threadIdx.x;
    if (bid < 512){
        // ---------------- embed_xw ----------------
        int r0 = bid * 8;
        if (tid < 8){
            int r = r0 + tid; int t = r >> 4, n = r & 15;
            toks[tid] = captions[n*257 + t];
        }
        __syncthreads();
        for (int i = 0; i < 8; ++i){
            int lin = tid + i*256;
            int ri = lin >> 8, d = lin & 255;
            xs[ri][d] = Wemb[(long)toks[ri]*WORDVEC + d];
        }
        __syncthreads();
        float4 b0 = *(const float4*)(b + tid*4);
        float4 b1 = *(const float4*)(b + 1024 + tid*4);
        float acc[8][8];
        for (int ri = 0; ri < 8; ++ri){
            acc[ri][0]=b0.x; acc[ri][1]=b0.y; acc[ri][2]=b0.z; acc[ri][3]=b0.w;
            acc[ri][4]=b1.x; acc[ri][5]=b1.y; acc[ri][6]=b1.z; acc[ri][7]=b1.w;
        }
        for (int d = 0; d < WORDVEC; ++d){
            float4 w0 = *(const float4*)(Wx + (long)d*GATES + tid*4);
            float4 w1 = *(const float4*)(Wx + (long)d*GATES + 1024 + tid*4);
            #pragma unroll
            for (int ri = 0; ri < 8; ++ri){
                float xv = xs[ri][d];
                acc[ri][0] += xv*w0.x; acc[ri][1] += xv*w0.y;
                acc[ri][2] += xv*w0.z; acc[ri][3] += xv*w0.w;
                acc[ri][4] += xv*w1.x; acc[ri][5] += xv*w1.y;
                acc[ri][6] += xv*w1.z; acc[ri][7] += xv*w1.w;
            }
        }
        for (int ri = 0; ri < 8; ++ri){
            float4 o0 = {acc[ri][0],acc[ri][1],acc[ri][2],acc[ri][3]};
            float4 o1 = {acc[ri][4],acc[ri][5],acc[ri][6],acc[ri][7]};
            *(float4*)(xw + (long)(r0+ri)*GATES + tid*4) = o0;
            *(float4*)(xw + (long)(r0+ri)*GATES + 1024 + tid*4) = o1;
        }
    } else if (bid < 544){
        // ---------------- whp_prep ----------------
        int w = bid - 512;
        for (int item = tid; item < 4096; item += 256){
            int f = item >> 6;          // 0..63
            int L = item & 63;
            int kt = f >> 2, nt = f & 3;
            int q = L >> 4, ln = L & 15;
            int col = nt*HIDDEN + w*16 + ln;   // gate nt, unit w*16+ln
            short8 vvec;
            for (int jj = 0; jj < 8; ++jj){
                int k = kt*32 + q*8 + jj;
                vvec[jj] = (short)f2bf(Wh[(long)k*GATES + col]);
            }
            *(short8*)(Whp + ((long)w*4096 + item)*8) = vvec;
        }
    } else if (bid < 560){
        // ---------------- hg_init (+ progress zero) ----------------
        if (bid == 544 && tid < 32) prog[tid] = 0;
        int p = (bid - 544)*256 + tid;   // 4096 pairs
        int fq = p >> 6;
        int j  = (p & 3) * 2;
        int u0 = (fq>>2)*32 + (fq&3)*8 + j;
        u64 pk = (u64)f2bf(h_init[u0]) | ((u64)f2bf(h_init[u0+1]) << 16);   // tag 0
        hx[p] = pk;
    } else {
        // ---------------- wv_pack ----------------
        int tile = bid - 560;               // 0..3999
        int v0 = (tile >> 3) * 64;          // 500 column-tiles
        int k0 = (tile & 7) * 64;           // 8 row-tiles
        for (int i = 0; i < 16; ++i){
            int lin = tid + i*256;
            int kk = lin >> 6, vv = lin & 63;
            s[kk][vv] = Wv[(long)(k0+kk)*VOCAB + v0 + vv];
        }
        __syncthreads();
        for (int i = 0; i < 2; ++i){
            int lr = tid + i*256;          // 0..511 lane-rows
            int f  = lr >> 6;              // 0..7: vbl(0..3) x ktl(0..1)
            int vbl = f >> 1, ktl = f & 1;
            int L = lr & 63, q = L >> 4, ln = L & 15;
            short8 o;
            #pragma unroll
            for (int j = 0; j < 8; ++j)
                o[j] = (short)f2bf(s[ktl*32 + q*8 + j][vbl*16 + ln]);
            long vb = (long)(tile >> 3)*4 + vbl;
            long kt = (long)(tile & 7)*2 + ktl;
            *(short8*)(WvP + ((vb*16 + kt)*64 + L)*8) = o;
        }
    }
}

// ---------------------------------------------------------------- K2:
// Fused LSTM + vocab GEMM.
//   blocks [0,32):      verified LSTM recurrence (tagged-u64 agent exchange);
//                       hsP published via agent-scope u32 pair-stores;
//                       every 16 steps: vmcnt drain + barrier + prog[w]=chunk.
//   blocks [32,8032):   vocab GEMM (BM=64, BN=256) ordered by readiness group;
//                       XCD-banded within a group.
// Round-9 fix: target-logit grab was runtime-indexing acc (acc[mt][nt][r]
// with nt = tg>>4) -> the WHOLE accumulator array lived in SCRATCH since
// round 1 (rule #20). ~1 GB/dispatch of asymmetric scratch writes across
// rounds 6-8. Now fully static (mt,nt,r) sweep -> acc in VGPRs.
__global__ __launch_bounds__(256) void lstm_vocab(const float* __restrict__ xw,
        const unsigned short* __restrict__ Whp, u64* __restrict__ hx,
        unsigned short* __restrict__ hsP, int* __restrict__ prog,
        const unsigned short* __restrict__ WvP, const float* __restrict__ bvoc,
        const int* __restrict__ captions, float* __restrict__ pmax,
        float* __restrict__ psum, float* __restrict__ tlog){
    __shared__ unsigned int hstage[4096];   // 16 KB (lstm role)
    __shared__ float a_s[4][16][16];        // 4 KB  (lstm role)
    __shared__ int   tgt_s[64];             // vocab role
    __shared__ float wmax_s[4][64], wsum_s[4][64];
    int tid = threadIdx.x;       // 0..255

    if (blockIdx.x >= NWG){
        // ================= vocab role =================
        int vid = blockIdx.x - NWG;         // 0..7999
        int pri = vid / 2000;               // readiness group
        int idx = vid % 2000;
        // XCD banding: same-XCD blocks get contiguous (bn, all-16-bm) runs.
        int p   = (idx & 7)*250 + (idx >> 3);   // bijective within [0,2000)
        int bn  = p >> 4;                   // 0..124
        int bm  = (p & 15)*4 + pri;         // bm in group pri (bm&3 == pri)
        int need = (pri + 1) * 4;           // lstm chunks (16 steps each) required

        if (tid == 0){
            int cnt = 0;
            for (;;){
                int mn = 1 << 30;
                for (int i = 0; i < 32; ++i){
                    int pv = AGLOAD(&prog[i]);
                    mn = pv < mn ? pv : mn;
                }
                if (mn >= need) break;
                __builtin_amdgcn_s_sleep(32);
                if (++cnt > SPINCAP) break;   // escape hatch (never in practice)
            }
        }
        __syncthreads();

        int wv = tid >> 6, L = tid & 63;
        int q = L >> 4, ln = L & 15;
        if (tid < 64){
            int rg = bm*64 + tid;
            tgt_s[tid] = captions[(rg >> 8)*257 + (rg & 255) + 1];
        }
        __syncthreads();
        f32x4 acc[4][4];
        for (int mt=0;mt<4;++mt) for (int nt=0;nt<4;++nt) acc[mt][nt] = (f32x4){0.f,0.f,0.f,0.f};
        int colb = bn*256 + wv*64;
        // u16 bases incl. lane offset; frag stride 512 u16 (1KB), mt/nt stride 8192 u16
        const unsigned short* aB = hsP + ((long)(bm*4)*16)*512 + (long)L*8;
        const unsigned short* bB = WvP + ((long)(bn*16 + wv*4)*16)*512 + (long)L*8;
        #pragma unroll 1
        for (int kt = 0; kt < 16; ++kt){
            const short8* aK = (const short8*)(aB + (long)kt*512);   // short8 idx: *16B
            const short8* bK = (const short8*)(bB + (long)kt*512);
            // G(m01,n01)
            short8 a0 = aK[0],    a1 = aK[1024];
            short8 b0 = bK[0],    b1 = bK[1024];
            acc[0][0] = MFMA16(a0,b0,acc[0][0]); acc[0][1] = MFMA16(a0,b1,acc[0][1]);
            acc[1][0] = MFMA16(a1,b0,acc[1][0]); acc[1][1] = MFMA16(a1,b1,acc[1][1]);
            __builtin_amdgcn_sched_barrier(0);
            // G(m01,n23): reuse a0,a1
            short8 b2 = bK[2048], b3 = bK[3072];
            acc[0][2] = MFMA16(a0,b2,acc[0][2]); acc[0][3] = MFMA16(a0,b3,acc[0][3]);
            acc[1][2] = MFMA16(a1,b2,acc[1][2]); acc[1][3] = MFMA16(a1,b3,acc[1][3]);
            __builtin_amdgcn_sched_barrier(0);
            // G(m23,n23): reuse b2,b3
            short8 a2 = aK[2048], a3 = aK[3072];
            acc[2][2] = MFMA16(a2,b2,acc[2][2]); acc[2][3] = MFMA16(a2,b3,acc[2][3]);
            acc[3][2] = MFMA16(a3,b2,acc[3][2]); acc[3][3] = MFMA16(a3,b3,acc[3][3]);
            __builtin_amdgcn_sched_barrier(0);
            // G(m23,n01): reuse a2,a3; reload b0,b1 via opaque addr (liveness cap)
            u64 bKo = (u64)bK; asm volatile("" : "+v"(bKo));
            const short8* bK2 = (const short8*)bKo;
            short8 c0 = bK2[0], c1 = bK2[1024];
            acc[2][0] = MFMA16(a2,c0,acc[2][0]); acc[2][1] = MFMA16(a2,c1,acc[2][1]);
            acc[3][0] = MFMA16(a3,c0,acc[3][0]); acc[3][1] = MFMA16(a3,c1,acc[3][1]);
            __builtin_amdgcn_sched_barrier(0);
        }
        float bv[4];
        #pragma unroll
        for (int nt=0;nt<4;++nt) bv[nt] = bvoc[colb + nt*16 + ln];
        #pragma unroll
        for (int mt=0;mt<4;++mt) for (int nt=0;nt<4;++nt) for (int r=0;r<4;++r)
            acc[mt][nt][r] += bv[nt];
        // target-logit grab — fully STATIC (mt,nt,r) sweep; tg == nt*16+ln
        // is equivalent to (0<=tg<64 && tg>>4==nt && (tg&15)==ln).
        #pragma unroll
        for (int mt=0;mt<4;++mt)
            #pragma unroll
            for (int nt=0;nt<4;++nt)
                #pragma unroll
                for (int r=0;r<4;++r){
                    int rl = mt*16 + q*4 + r;
                    int tg = tgt_s[rl] - colb;
                    if (tg == nt*16 + ln) tlog[bm*64 + rl] = acc[mt][nt][r];
                }
        // per-row max & sumexp over this block's 256 cols
        #pragma unroll
        for (int mt=0;mt<4;++mt){
            #pragma unroll
            for (int r=0;r<4;++r){
                float m = fmaxf(fmaxf(acc[mt][0][r],acc[mt][1][r]), fmaxf(acc[mt][2][r],acc[mt][3][r]));
                for (int d=1; d<16; d<<=1) m = fmaxf(m, __shfl_xor(m, d, 16));
                float s = __expf(acc[mt][0][r]-m) + __expf(acc[mt][1][r]-m)
                        + __expf(acc[mt][2][r]-m) + __expf(acc[mt][3][r]-m);
                for (int d=1; d<16; d<<=1) s += __shfl_xor(s, d, 16);
                if (ln == 0){ int rl = mt*16 + q*4 + r; wmax_s[wv][rl] = m; wsum_s[wv][rl] = s; }
            }
        }
        __syncthreads();
        if (tid < 64){
            float M = fmaxf(fmaxf(wmax_s[0][tid],wmax_s[1][tid]), fmaxf(wmax_s[2][tid],wmax_s[3][tid]));
            float S = 0.f;
            for (int ww=0; ww<4; ++ww) S += wsum_s[ww][tid]*__expf(wmax_s[ww][tid]-M);
            pmax[(long)bn*NROWS + bm*64 + tid] = M;
            psum[(long)bn*NROWS + bm*64 + tid] = S;
        }
        return;
    }

    // ================= lstm role (verified round-1 protocol) =================
    int w = blockIdx.x;          // 0..31
    int wv = tid >> 6;           // wave = gate = N-tile (0..3)
    int L = tid & 63;
    int q = L >> 4, ln = L & 15;
    int s_idx = tid >> 4, jl = tid & 15;   // (sequence, local hidden unit)

    // Wh B-fragments -> registers (wave wv uses fragments kt*4+wv only)
    short8 bw[16];
    #pragma unroll
    for (int kt = 0; kt < 16; ++kt)
        bw[kt] = *(const short8*)(Whp + ((long)w*4096 + (kt*4+wv)*64 + L)*8);

    float c_r = 0.f;
    int fq_pub = (w>>1)*4 + (w&1)*2 + (jl>>3);
    int pubIdx = fq_pub*64 + s_idx*4 + ((jl>>1)&3);
    int kt_h = w >> 1;
    int q_h  = ((w & 1) << 1) | (jl >> 3);
    int j_h  = jl & 7;
    unsigned int* hsP32 = (unsigned int*)hsP;

    for (int t = 0; t < TSTEPS; ++t){
        // xw loads first: HBM latency overlaps the poll
        long xb = (long)(t*16 + s_idx)*GATES + w*16 + jl;
        float xg0 = xw[xb], xg1 = xw[xb+512], xg2 = xw[xb+1024], xg3 = xw[xb+1536];

        const u64* hr = hx + (t & 1)*4096;
        u64*       hw = hx + ((t+1) & 1)*4096;

        // ---- poll + stage: 16 coalesced u64/thread, spin until all tags == t
        u64 v[16];
        #pragma unroll
        for (int i = 0; i < 16; ++i)
            v[i] = AGLOAD(hr + tid + i*256);
        for (;;){
            u64 bad = 0;
            #pragma unroll
            for (int i = 0; i < 16; ++i) bad |= (v[i] >> 32) ^ (u64)(unsigned)t;
            if (!bad) break;
            #pragma unroll
            for (int i = 0; i < 16; ++i)
                v[i] = AGLOAD(hr + tid + i*256);
        }
        #pragma unroll
        for (int i = 0; i < 16; ++i) hstage[tid + i*256] = (unsigned)v[i];
        __syncthreads();   // S1: stage complete (also orders vs prev a_s reads)

        // ---- MFMA: A-frag (kt,q,ln) = 4 contiguous u32 (linear sweep)
        f32x4 acc = {0.f,0.f,0.f,0.f};
        #pragma unroll
        for (int kt = 0; kt < 16; ++kt){
            short8 a = *(const short8*)((const unsigned short*)hstage + (kt*256 + q*64 + ln*4)*2);
            acc = MFMA16(a, bw[kt], acc);
        }
        #pragma unroll
        for (int r = 0; r < 4; ++r) a_s[wv][q*4 + r][ln] = acc[r];
        __syncthreads();   // S2: a_s complete (also: all hstage reads done)

        // ---- gate phase
        float ai = a_s[0][s_idx][jl] + xg0;
        float af = a_s[1][s_idx][jl] + xg1;
        float ao = a_s[2][s_idx][jl] + xg2;
        float ag = a_s[3][s_idx][jl] + xg3;
        float ig = 1.f/(1.f + __expf(-ai));
        float fg = 1.f/(1.f + __expf(-af));
        float og = 1.f/(1.f + __expf(-ao));
        float gg = 2.f/(1.f + __expf(-2.f*ag)) - 1.f;
        c_r = fg*c_r + ig*gg;
        float hv = og * (2.f/(1.f + __expf(-2.f*c_r)) - 1.f);
        unsigned short hb = f2bf(hv);

        // ---- publish h (tagged u64) + hsP (agent u32 pair), fire-and-forget
        int hv32 = (int)hb;
        int other = __shfl(hv32, L ^ 1);
        int rb = s_idx*16 + (t >> 4);
        if ((jl & 1) == 0){
            u64 pk = (u64)(unsigned short)hv32
                   | ((u64)(unsigned short)other << 16)
                   | ((u64)(unsigned)(t+1) << 32);
            __hip_atomic_store(hw + pubIdx, pk, __ATOMIC_RELAXED, __HIP_MEMORY_SCOPE_AGENT);
            unsigned int hp = (unsigned int)(unsigned short)hv32
                            | ((unsigned int)(unsigned short)other << 16);
            // u32 index = u16 index / 2 (j_h is even here)
            __hip_atomic_store(hsP32 + (((long)(rb*16 + kt_h))*64 + q_h*16 + (t & 15))*4 + (j_h >> 1),
                               hp, __ATOMIC_RELAXED, __HIP_MEMORY_SCOPE_AGENT);
        }
        // ---- chunk boundary: drain stores, then publish progress
        if ((t & 15) == 15){
            asm volatile("s_waitcnt vmcnt(0)" ::: "memory");
            __syncthreads();
            if (tid == 0)
                __hip_atomic_store(&prog[w], (t >> 4) + 1, __ATOMIC_RELAXED, __HIP_MEMORY_SCOPE_AGENT);
        }
    }
}

// ---------------------------------------------------------------- K4:
// combine 125 partials per row -> lse -> masked NLL -> loss/N
__global__ __launch_bounds__(256) void reduce_loss(const float* __restrict__ pmax,
        const float* __restrict__ psum, const float* __restrict__ tlog,
        const int* __restrict__ captions, float* __restrict__ out){
    int r = blockIdx.x*256 + threadIdx.x;
    float M = -1e30f;
    #pragma unroll 5
    for (int p=0;p<NVB;++p) M = fmaxf(M, pmax[(long)p*NROWS + r]);
    float S = 0.f;
    #pragma unroll 5
    for (int p=0;p<NVB;++p) S += psum[(long)p*NROWS + r]*__expf(pmax[(long)p*NROWS + r]-M);
    float lse = M + logf(S);
    float nll = lse - tlog[r];
    int tok = captions[(r >> 8)*257 + (r & 255) + 1];
    float val = (tok != 0) ? nll : 0.f;
    __shared__ float red[256];
    red[threadIdx.x] = val; __syncthreads();
    for (int s=128; s>0; s>>=1){
        if (threadIdx.x < s) red[threadIdx.x] += red[threadIdx.x+s];
        __syncthreads();
    }
    if (threadIdx.x == 0) atomicAdd(out, red[0] * (1.0f/16.0f));
}

// ---------------------------------------------------------------- launch
extern "C" void kernel_launch(void* const* d_in, const int* in_sizes, int n_in,
                              void* d_out, int out_size, void* d_ws, size_t ws_size,
                              hipStream_t stream){
    const int*   captions = (const int*)  d_in[0];
    const float* Wemb     = (const float*)d_in[1];
    const float* Wx       = (const float*)d_in[2];
    const float* Wh       = (const float*)d_in[3];
    const float* b        = (const float*)d_in[4];
    const float* Wv       = (const float*)d_in[5];
    const float* bvoc     = (const float*)d_in[6];
    const float* h_init   = (const float*)d_in[7];

    char* ws = (char*)d_ws;
    float*          xw   = (float*)         (ws + 0);          // 33554432 B
    unsigned short* WvP  = (unsigned short*)(ws + 33554432);   // 32768000 B
    unsigned short* hsP  = (unsigned short*)(ws + 66322432);   //  4194304 B
    float*          pmax = (float*)         (ws + 70516736);   //  2048000 B
    float*          psum = (float*)         (ws + 72564736);   //  2048000 B
    float*          tlog = (float*)         (ws + 74612736);   //    16384 B
    unsigned short* Whp  = (unsigned short*)(ws + 74629120);   //  2097152 B
    u64*            hx   = (u64*)           (ws + 76726272);   //    65536 B (2 bufs x 4096 u64)
    int*            prog = (int*)           (ws + 76791808);   //      128 B (32 progress ctrs)

    float* out_f = (float*)d_out;

    (void)hipMemsetAsync(d_out, 0, sizeof(float), stream);

    hipLaunchKernelGGL(prep_all,    dim3(4560),       dim3(256), 0, stream,
                       captions, Wemb, Wx, b, xw, Wh, Whp, h_init, hx, Wv, WvP, prog);
    hipLaunchKernelGGL(lstm_vocab,  dim3(NWG+NVBLK),  dim3(256), 0, stream,
                       xw, Whp, hx, hsP, prog, WvP, bvoc, captions, pmax, psum, tlog);
    hipLaunchKernelGGL(reduce_loss, dim3(16),         dim3(256), 0, stream,
                       pmax, psum, tlog, captions, out_f);
}